// Round 7
// baseline (660.096 us; speedup 1.0000x reference)
//
#include <hip/hip_runtime.h>
#include <hip/hip_bf16.h>

// B=4, T=2048, C=1024, H=16, HD=64. JOINED_DIM=25 (mask col%25==24 -> masked).

typedef __attribute__((ext_vector_type(8))) short short8;
typedef __attribute__((ext_vector_type(4))) short short4v;
typedef __attribute__((ext_vector_type(4))) float floatx4;
typedef unsigned short us;

__device__ __forceinline__ us f2bf(float f){
    union { __hip_bfloat16 h; us u; } cv;
    cv.h = __float2bfloat16(f);
    return cv.u;
}

__device__ __forceinline__ void ld_g2l16(const void* g, void* l){
    __builtin_amdgcn_global_load_lds((const __attribute__((address_space(1))) void*)g,
                                     (__attribute__((address_space(3))) void*)l, 16, 0, 0);
}

// ---------------- fp32 -> bf16 conversion ----------------
__global__ __launch_bounds__(256) void cvt_kernel(const float* __restrict__ in,
                                                  us* __restrict__ out, int n4){
    int i = blockIdx.x * 256 + threadIdx.x;
    if (i < n4){
        float4 v = reinterpret_cast<const float4*>(in)[i];
        ushort4 o;
        o.x = f2bf(v.x); o.y = f2bf(v.y); o.z = f2bf(v.z); o.w = f2bf(v.w);
        reinterpret_cast<ushort4*>(out)[i] = o;
    }
}

__global__ __launch_bounds__(256) void cvt4_kernel(const float* __restrict__ w0, const float* __restrict__ w1,
                                                   const float* __restrict__ w2, const float* __restrict__ w3,
                                                   us* __restrict__ o0, us* __restrict__ o1,
                                                   us* __restrict__ o2, us* __restrict__ o3){
    int wsel = blockIdx.x >> 10;
    int i = (blockIdx.x & 1023) * 256 + threadIdx.x;
    const float* src = (wsel == 0) ? w0 : (wsel == 1) ? w1 : (wsel == 2) ? w2 : w3;
    us* dst = (wsel == 0) ? o0 : (wsel == 1) ? o1 : (wsel == 2) ? o2 : o3;
    float4 v = reinterpret_cast<const float4*>(src)[i];
    ushort4 o;
    o.x = f2bf(v.x); o.y = f2bf(v.y); o.z = f2bf(v.z); o.w = f2bf(v.w);
    reinterpret_cast<ushort4*>(dst)[i] = o;
}

// ---------------- merged QKV GEMM: 256x256 tile, 64x128 wave tiles, dbuf + E/O read-ahead ----------------
// Round-7 change: wave tile 64x64 -> 64x128 (4M x 2N over a 256x256 block tile). LDS-read
// bytes per FLOP drop 30.5 -> 22.9 B/kFLOP; per phase per CU: MFMA 1242 cyc > LDS reads
// 1129 cyc -> matrix pipe becomes the floor (was LDS at the old geometry, which capped
// MfmaUtil at ~45% even with perfect overlap). Double-buffered LDS 2 x 64 KB = 128 KiB.
// Pipeline (E/O register sets, proven round 6):
//   P1(t): read (t,ks1)->O | stage tile t+1 -> buf^1 | MFMA(E=(t,ks0)) | lgkm0 | vmcnt(0) | bar
//          (staging drains under the 32-MFMA cluster; ~1242 cyc covers ~900 cyc HBM latency)
//   P2(t): read (t+1,ks0)->E (buf^1 staged+fenced) | MFMA(O=(t,ks1)) | lgkm0 | bar
// WAR: buf^1 held tile t-1; its last reads (P1(t-1)) are lgkm-drained before that barrier.
// acc 128 VGPR + E/O frags 96 -> ~245, fits 256-cap at 2 waves/SIMD (launch_bounds 512,2).

#define QSCALE 0.1803368801111244f

#define BAR() __builtin_amdgcn_s_barrier()
#define SGB0() __builtin_amdgcn_sched_barrier(0)
#define LGKM0() do { asm volatile("s_waitcnt lgkmcnt(0)" ::: "memory"); __builtin_amdgcn_sched_barrier(0); } while(0)
#define VMC0() asm volatile("s_waitcnt vmcnt(0)" ::: "memory")

#define STAGE_A4(buf, kt) do { \
    _Pragma("unroll") \
    for (int c_ = 0; c_ < 4; c_++) \
        ld_g2l16(Ag + (size_t)(m0 + srow[c_])*1024 + (kt)*64 + sgr[c_]*8, \
                 &smem[(buf)*32768 + (c_*8 + wave)*512]); \
} while(0)

#define STAGE_B4(buf, kt) do { \
    _Pragma("unroll") \
    for (int c_ = 0; c_ < 4; c_++) \
        ld_g2l16(Wb + (size_t)(n0 + srow[c_])*1024 + (kt)*64 + sgr[c_]*8, \
                 &smem[(buf)*32768 + 16384 + (c_*8 + wave)*512]); \
} while(0)

// load A(4) + B(8) fragments of k-slice KS from buffer `buf` into register set AF/BF
#define LOAD_SET4(buf, KS, AF, BF) do { \
    _Pragma("unroll") \
    for (int i_ = 0; i_ < 4; i_++){ \
        int ra_ = wmm*64 + i_*16 + lane15; \
        int ga_ = ((KS)*4 + quad) ^ (ra_ & 7); \
        AF[i_] = *reinterpret_cast<const short8*>(&smem[(buf)*32768 + ra_*64 + ga_*8]); \
    } \
    _Pragma("unroll") \
    for (int j_ = 0; j_ < 8; j_++){ \
        int rb_ = wnn*128 + j_*16 + lane15; \
        int gb_ = ((KS)*4 + quad) ^ (rb_ & 7); \
        BF[j_] = *reinterpret_cast<const short8*>(&smem[(buf)*32768 + 16384 + rb_*64 + gb_*8]); \
    } \
} while(0)

#define MFMA_SET4(AF, BF) do { \
    __builtin_amdgcn_s_setprio(1); \
    _Pragma("unroll") \
    for (int i_ = 0; i_ < 4; i_++) \
        _Pragma("unroll") \
        for (int j_ = 0; j_ < 8; j_++) \
            acc[i_][j_] = __builtin_amdgcn_mfma_f32_16x16x32_bf16( \
                AF[i_], BF[j_], acc[i_][j_], 0, 0, 0); \
    __builtin_amdgcn_s_setprio(0); \
} while(0)

#define KLOOP4() do { \
    STAGE_A4(0, 0); STAGE_B4(0, 0); \
    VMC0(); BAR(); \
    LOAD_SET4(0, 0, afE, bfE); LGKM0(); \
    _Pragma("unroll 2") \
    for (int t = 0; t < 16; t++){ \
        const int cur = t & 1, nxt = cur ^ 1; \
        LOAD_SET4(cur, 1, afO, bfO); \
        SGB0(); \
        if (t < 15){ STAGE_A4(nxt, t + 1); STAGE_B4(nxt, t + 1); } \
        MFMA_SET4(afE, bfE); \
        LGKM0(); \
        if (t < 15) VMC0(); \
        BAR(); \
        if (t < 15){ LOAD_SET4(nxt, 0, afE, bfE); SGB0(); } \
        MFMA_SET4(afO, bfO); \
        LGKM0(); \
        BAR(); \
    } \
} while(0)

__global__ __launch_bounds__(512, 2) void gemm_qkv4(
    const us* __restrict__ Ag,
    const us* __restrict__ Wqb, const us* __restrict__ Wkb, const us* __restrict__ Wvb,
    const float* __restrict__ bq, const float* __restrict__ bk, const float* __restrict__ bv,
    us* __restrict__ qo, us* __restrict__ ko, us* __restrict__ vto)
{
    __shared__ us smem[65536];   // 2 x (A 16384 us + B 16384 us) = 128 KiB
    const int tid = threadIdx.x;
    const int lane = tid & 63;
    const int wave = tid >> 6;        // 0..7
    const int lane15 = lane & 15;
    const int quad = lane >> 4;
    const int wmm = wave & 3;         // 0..3 (64 rows each)
    const int wnn = wave >> 2;        // 0..1 (128 cols each)
    const int seg = blockIdx.x >> 2;          // 0=Q 1=K 2=V
    const int n0 = (blockIdx.x & 3) * 256;
    const int m0 = blockIdx.y * 256;

    const us* Wb = (seg == 0) ? Wqb : (seg == 1) ? Wkb : Wvb;
    const float* bias = (seg == 0) ? bq : (seg == 1) ? bk : bv;

    int srow[4], sgr[4];
    #pragma unroll
    for (int c = 0; c < 4; c++){
        int s = (c*8 + wave)*64 + lane;
        srow[c] = s >> 3;                       // 0..255
        sgr[c] = (s & 7) ^ ((s >> 3) & 7);
    }

    floatx4 zero = {0.f, 0.f, 0.f, 0.f};
    floatx4 acc[4][8];
    #pragma unroll
    for (int i = 0; i < 4; i++)
        #pragma unroll
        for (int j = 0; j < 8; j++) acc[i][j] = zero;
    short8 afE[4], bfE[8], afO[4], bfO[8];

    KLOOP4();

    if (seg < 2){
        #pragma unroll
        for (int i = 0; i < 4; i++){
            #pragma unroll
            for (int j = 0; j < 8; j++){
                int n = n0 + wnn*128 + j*16 + lane15;
                float bvv = bias[n];
                #pragma unroll
                for (int r = 0; r < 4; r++){
                    int m = m0 + wmm*64 + i*16 + quad*4 + r;
                    float val = acc[i][j][r] + bvv;
                    if (seg == 0){
                        qo[(size_t)m*1024 + n] = f2bf(val * QSCALE);
                    } else {
                        int b = m >> 11, tt = m & 2047;
                        int h = n >> 6,  d = n & 63;
                        ko[(((size_t)b*16 + h)*2048 + tt)*64 + d] = f2bf(val);
                    }
                }
            }
        }
    } else {
        // V^T epilogue: 256m x 256n transpose via LDS, two 128-col passes.
        // Pass p: waves with wnn==p write their acc into lCT [128 n][264 us];
        // all 512 threads copy out with RL-masked columns (t%25==24) zeroed.
        us* lCT = smem;                  // 128*264 = 33792 us <= 65536
        const int b = m0 >> 11;
        const int t0 = m0 & 2047;
        #pragma unroll
        for (int p = 0; p < 2; p++){
            if (p) __syncthreads();
            if (wnn == p){
                #pragma unroll
                for (int j = 0; j < 8; j++){
                    int nl = j*16 + lane15;              // 0..127 within pass
                    float bvv = bias[n0 + p*128 + nl];
                    #pragma unroll
                    for (int i = 0; i < 4; i++){
                        int ml = wmm*64 + i*16 + quad*4; // 0..255
                        unsigned int lo = (unsigned int)f2bf(acc[i][j][0] + bvv) |
                                          ((unsigned int)f2bf(acc[i][j][1] + bvv) << 16);
                        unsigned int hi = (unsigned int)f2bf(acc[i][j][2] + bvv) |
                                          ((unsigned int)f2bf(acc[i][j][3] + bvv) << 16);
                        uint2 pk2; pk2.x = lo; pk2.y = hi;
                        *reinterpret_cast<uint2*>(&lCT[(size_t)nl*264 + ml]) = pk2;
                    }
                }
            }
            __syncthreads();
            int nl = tid >> 2;           // 0..127
            int c4 = tid & 3;            // 64-us segment of the 256-wide row
            int nC = n0 + p*128 + nl;
            int h = nC >> 6, d = nC & 63;
            us* dst = vto + (((size_t)b*16 + h)*64 + d)*2048 + t0 + c4*64;
            int rr = (t0 + c4*64) % 25;
            #pragma unroll
            for (int ii = 0; ii < 8; ii++){
                uint4 v = *reinterpret_cast<const uint4*>(&lCT[(size_t)nl*264 + c4*64 + ii*8]);
                us* pv = reinterpret_cast<us*>(&v);
                #pragma unroll
                for (int e = 0; e < 8; e++){
                    if (rr == 24) pv[e] = 0;
                    rr = (rr == 24) ? 0 : rr + 1;
                }
                *reinterpret_cast<uint4*>(dst + ii*8) = v;
            }
        }
    }
}

// ---------------- Flash attention v3 (unchanged from round 4) ----------------
__device__ __forceinline__ short8 rdP(const us* pw, int lane15, int ks, int quad){
    const us* a = &pw[lane15*68 + ks*32 + quad*8];
    short4v lo = *reinterpret_cast<const short4v*>(a);
    short4v hi = *reinterpret_cast<const short4v*>(a + 4);
    short8 r = {lo[0], lo[1], lo[2], lo[3], hi[0], hi[1], hi[2], hi[3]};
    return r;
}

__device__ __forceinline__ void pstore_plain(floatx4 (&s)[4], us* pw, int lane15, int quad){
    #pragma unroll
    for (int tj = 0; tj < 4; tj++)
        #pragma unroll
        for (int r = 0; r < 4; r++)
            pw[(quad*4 + r)*68 + tj*16 + lane15] = f2bf(__builtin_amdgcn_exp2f(s[tj][r]));
}

__device__ __forceinline__ void pstore_diag(floatx4 (&s)[4], us* pw, int rgrow, int j0,
                                            int lane15, int quad){
    #pragma unroll
    for (int tj = 0; tj < 4; tj++){
        #pragma unroll
        for (int r = 0; r < 4; r++){
            float p = __builtin_amdgcn_exp2f(s[tj][r]);
            bool kill = (j0 + tj*16 + lane15) > (rgrow + quad*4 + r);
            pw[(quad*4 + r)*68 + tj*16 + lane15] = f2bf(kill ? 0.f : p);
        }
    }
}

#define ATT_STAGE(itn) do { \
    _Pragma("unroll") \
    for (int i_ = 0; i_ < 2; i_++){ \
        ld_g2l16(kb + (size_t)((itn)*64 + srow[i_])*64 + sgr[i_]*8, &lK[(itn) & 1][(i_*4 + wave)*512]); \
        ld_g2l16(vb + (size_t)srow[i_]*2048 + (itn)*64 + sgr[i_]*8, &lV[(itn) & 1][(i_*4 + wave)*512]); \
    } } while(0)

// MODE 0: both rg, no diag. MODE 1: rg0 diag, rg1 plain. MODE 2: rg1 diag, rg0 inactive.
#define ATT_BODY(MODE, ITV) do { \
    const int j0_ = (ITV)*64; \
    __syncthreads(); \
    if ((ITV) + 1 < nIter) ATT_STAGE((ITV) + 1); \
    const us* Kb = lK[(ITV) & 1]; \
    const us* Vb = lV[(ITV) & 1]; \
    floatx4 s0[4], s1[4]; \
    __builtin_amdgcn_s_setprio(1); \
    _Pragma("unroll") \
    for (int tj = 0; tj < 4; tj++){ \
        int rk = tj*16 + lane15; \
        short8 kf0 = *reinterpret_cast<const short8*>(&Kb[rk*64 + ((quad     ^ (rk & 7)))*8]); \
        short8 kf1 = *reinterpret_cast<const short8*>(&Kb[rk*64 + (((4+quad) ^ (rk & 7)))*8]); \
        floatx4 z1 = __builtin_amdgcn_mfma_f32_16x16x32_bf16(qf1a, kf0, zero, 0, 0, 0); \
        s1[tj]     = __builtin_amdgcn_mfma_f32_16x16x32_bf16(qf1b, kf1, z1,   0, 0, 0); \
        if ((MODE) != 2){ \
            floatx4 z0 = __builtin_amdgcn_mfma_f32_16x16x32_bf16(qf0a, kf0, zero, 0, 0, 0); \
            s0[tj]     = __builtin_amdgcn_mfma_f32_16x16x32_bf16(qf0b, kf1, z0,   0, 0, 0); \
        } \
    } \
    __builtin_amdgcn_s_setprio(0); \
    if ((MODE) == 2)      pstore_diag(s1, pw1, rg1, j0_, lane15, quad); \
    else                  pstore_plain(s1, pw1, lane15, quad); \
    if ((MODE) == 1)      pstore_diag(s0, pw0, rg0, j0_, lane15, quad); \
    else if ((MODE) == 0) pstore_plain(s0, pw0, lane15, quad); \
    __builtin_amdgcn_s_setprio(1); \
    _Pragma("unroll") \
    for (int ks = 0; ks < 2; ks++){ \
        short8 mfr = *reinterpret_cast<const short8*>(&lmask[j0_ + ks*32 + quad*8]); \
        short8 pf1 = rdP(pw1, lane15, ks, quad); \
        short8 pf0; \
        lacc1 = __builtin_amdgcn_mfma_f32_16x16x32_bf16(pf1, mfr, lacc1, 0, 0, 0); \
        if ((MODE) != 2){ \
            pf0 = rdP(pw0, lane15, ks, quad); \
            lacc0 = __builtin_amdgcn_mfma_f32_16x16x32_bf16(pf0, mfr, lacc0, 0, 0, 0); \
        } \
        _Pragma("unroll") \
        for (int dt = 0; dt < 4; dt++){ \
            int rv = dt*16 + lane15; \
            short8 vf = *reinterpret_cast<const short8*>(&Vb[rv*64 + (((ks*4+quad) ^ (rv & 7)))*8]); \
            acc1[dt] = __builtin_amdgcn_mfma_f32_16x16x32_bf16(pf1, vf, acc1[dt], 0, 0, 0); \
            if ((MODE) != 2) acc0[dt] = __builtin_amdgcn_mfma_f32_16x16x32_bf16(pf0, vf, acc0[dt], 0, 0, 0); \
        } \
    } \
    __builtin_amdgcn_s_setprio(0); \
} while(0)

__global__ __launch_bounds__(256, 3) void flash_attn(
    const us* __restrict__ q,
    const us* __restrict__ k,
    const us* __restrict__ vT,
    us* __restrict__ y)
{
    __shared__ us lK[2][64*64];        // double-buffered K tile (XOR-swizzled)
    __shared__ us lV[2][64*64];        // double-buffered V^T tile
    __shared__ us lP[4][2][16*68];     // per-wave P buffers (stride 68)
    __shared__ us lmask[2048];         // bf16 column mask: t%25==24 -> 0 else 1
    const int tid = threadIdx.x;
    const int lane = tid & 63;
    const int wave = tid >> 6;
    const int lane15 = lane & 15;
    const int quad = lane >> 4;
    const int lin = blockIdx.x;        // grid 1024 = 16 qtiles x 64 bh, longest-first
    const int qt2 = 15 - (lin >> 6);
    const int bh = lin & 63;
    const int b = bh >> 4, h = bh & 15;
    const int rg0 = qt2*128 + wave*16;
    const int rg1 = rg0 + 64;
    const int nIter = 2*qt2 + 2;

    const us* kb = k  + (size_t)bh*2048*64;
    const us* vb = vT + (size_t)bh*64*2048;

    // build column-mask table (ordered before first use by the loop-head __syncthreads)
    {
        int c0 = tid * 8;
        int rr = c0 % 25;
        ushort4 mv[2];
        us* pm = reinterpret_cast<us*>(mv);
        #pragma unroll
        for (int e = 0; e < 8; e++){
            pm[e] = (rr == 24) ? (us)0 : (us)0x3F80;
            rr = (rr == 24) ? 0 : rr + 1;
        }
        *reinterpret_cast<uint4*>(&lmask[c0]) = *reinterpret_cast<uint4*>(mv);
    }

    floatx4 zero = {0.f, 0.f, 0.f, 0.f};
    us* pw0 = &lP[wave][0][0];
    us* pw1 = &lP[wave][1][0];

    int srow[2], sgr[2];
    #pragma unroll
    for (int i = 0; i < 2; i++){
        int s = (i*4 + wave)*64 + lane;
        srow[i] = s >> 3;
        sgr[i] = (s & 7) ^ ((s >> 3) & 7);
    }

    const us* q0 = q + ((size_t)b*2048 + rg0 + lane15)*1024 + h*64 + quad*8;
    const us* q1 = q + ((size_t)b*2048 + rg1 + lane15)*1024 + h*64 + quad*8;
    short8 qf0a = *reinterpret_cast<const short8*>(q0);
    short8 qf0b = *reinterpret_cast<const short8*>(q0 + 32);
    short8 qf1a = *reinterpret_cast<const short8*>(q1);
    short8 qf1b = *reinterpret_cast<const short8*>(q1 + 32);

    floatx4 acc0[4], acc1[4];
    #pragma unroll
    for (int d = 0; d < 4; d++){ acc0[d] = zero; acc1[d] = zero; }
    floatx4 lacc0 = zero, lacc1 = zero;

    // pre-stage tile 0 into buffer 0
    ATT_STAGE(0);

    int it = 0;
    #pragma unroll 1
    for (; it < nIter - 2; it++) ATT_BODY(0, it);
    ATT_BODY(1, it); it++;
    ATT_BODY(2, it);

    float rl0[4], rl1[4];
    #pragma unroll
    for (int r = 0; r < 4; r++){ rl0[r] = 1.0f / lacc0[r]; rl1[r] = 1.0f / lacc1[r]; }
    #pragma unroll
    for (int dt = 0; dt < 4; dt++){
        #pragma unroll
        for (int r = 0; r < 4; r++){
            int t0 = rg0 + quad*4 + r;
            int t1 = rg1 + quad*4 + r;
            int cc = h*64 + dt*16 + lane15;
            y[((size_t)b*2048 + t0)*1024 + cc] = f2bf(acc0[dt][r] * rl0[r]);
            y[((size_t)b*2048 + t1)*1024 + cc] = f2bf(acc1[dt][r] * rl1[r]);
        }
    }
}

// ---------------- output projection GEMM: same 256x256 dbuf template, fp32 out ----------------
__global__ __launch_bounds__(512, 2) void gemm_out4(
    const us* __restrict__ Ag,
    const us* __restrict__ Wb,
    const float* __restrict__ bias,
    float* __restrict__ out)
{
    __shared__ us smem[65536];
    const int tid = threadIdx.x;
    const int lane = tid & 63;
    const int wave = tid >> 6;
    const int lane15 = lane & 15;
    const int quad = lane >> 4;
    const int wmm = wave & 3;
    const int wnn = wave >> 2;
    const int n0 = blockIdx.x * 256;
    const int m0 = blockIdx.y * 256;

    int srow[4], sgr[4];
    #pragma unroll
    for (int c = 0; c < 4; c++){
        int s = (c*8 + wave)*64 + lane;
        srow[c] = s >> 3;
        sgr[c] = (s & 7) ^ ((s >> 3) & 7);
    }

    floatx4 zero = {0.f, 0.f, 0.f, 0.f};
    floatx4 acc[4][8];
    #pragma unroll
    for (int i = 0; i < 4; i++)
        #pragma unroll
        for (int j = 0; j < 8; j++) acc[i][j] = zero;
    short8 afE[4], bfE[8], afO[4], bfO[8];

    KLOOP4();

    #pragma unroll
    for (int i = 0; i < 4; i++){
        #pragma unroll
        for (int j = 0; j < 8; j++){
            int n = n0 + wnn*128 + j*16 + lane15;
            float bvv = bias[n];
            #pragma unroll
            for (int r = 0; r < 4; r++){
                int m = m0 + wmm*64 + i*16 + quad*4 + r;
                out[(size_t)m*1024 + n] = acc[i][j][r] + bvv;
            }
        }
    }
}

// ---------------- launch ----------------
extern "C" void kernel_launch(void* const* d_in, const int* in_sizes, int n_in,
                              void* d_out, int out_size, void* d_ws, size_t ws_size,
                              hipStream_t stream)
{
    const float* x  = (const float*)d_in[0];
    const float* Wq = (const float*)d_in[1];
    const float* bq = (const float*)d_in[2];
    const float* Wk = (const float*)d_in[3];
    const float* bk = (const float*)d_in[4];
    const float* Wv = (const float*)d_in[5];
    const float* bv = (const float*)d_in[6];
    const float* Wp = (const float*)d_in[7];
    const float* bp = (const float*)d_in[8];
    float* out = (float*)d_out;

    us* ws  = (us*)d_ws;
    us* xbf = ws;                          // [8192,1024]
    us* wqb = xbf + (size_t)8192*1024;
    us* wkb = wqb + (size_t)1024*1024;
    us* wvb = wkb + (size_t)1024*1024;
    us* wpb = wvb + (size_t)1024*1024;
    us* qws = wpb + (size_t)1024*1024;     // q [B,T,C] bf16 (pre-scaled, exp2 domain)
    us* kws = qws + (size_t)8388608;       // k [B,H,T,64]
    us* vtw = kws + (size_t)8388608;       // vT [B,H,64,T] (RL-masked cols zeroed)
    us* yws = vtw + (size_t)8388608;       // y [B,T,C] bf16

    cvt_kernel<<<8192, 256, 0, stream>>>(x, xbf, 2097152);
    cvt4_kernel<<<4096, 256, 0, stream>>>(Wq, Wk, Wv, Wp, wqb, wkb, wvb, wpb);

    gemm_qkv4<<<dim3(12, 32), 512, 0, stream>>>(xbf, wqb, wkb, wvb, bq, bk, bv, qws, kws, vtw);

    flash_attn<<<1024, 256, 0, stream>>>(qws, kws, vtw, yws);

    gemm_out4<<<dim3(4, 32), 512, 0, stream>>>(yws, wpb, bp, out);
}

// Round 8
// 325.449 us; speedup vs baseline: 2.0283x; 2.0283x over previous
//
#include <hip/hip_runtime.h>
#include <hip/hip_bf16.h>

// B=4, T=2048, C=1024, H=16, HD=64. JOINED_DIM=25 (mask col%25==24 -> masked).

typedef __attribute__((ext_vector_type(8))) short short8;
typedef __attribute__((ext_vector_type(4))) short short4v;
typedef __attribute__((ext_vector_type(4))) float floatx4;
typedef unsigned short us;

__device__ __forceinline__ us f2bf(float f){
    union { __hip_bfloat16 h; us u; } cv;
    cv.h = __float2bfloat16(f);
    return cv.u;
}

__device__ __forceinline__ void ld_g2l16(const void* g, void* l){
    __builtin_amdgcn_global_load_lds((const __attribute__((address_space(1))) void*)g,
                                     (__attribute__((address_space(3))) void*)l, 16, 0, 0);
}

// ---------------- fp32 -> bf16 conversion ----------------
__global__ __launch_bounds__(256) void cvt_kernel(const float* __restrict__ in,
                                                  us* __restrict__ out, int n4){
    int i = blockIdx.x * 256 + threadIdx.x;
    if (i < n4){
        float4 v = reinterpret_cast<const float4*>(in)[i];
        ushort4 o;
        o.x = f2bf(v.x); o.y = f2bf(v.y); o.z = f2bf(v.z); o.w = f2bf(v.w);
        reinterpret_cast<ushort4*>(out)[i] = o;
    }
}

__global__ __launch_bounds__(256) void cvt4_kernel(const float* __restrict__ w0, const float* __restrict__ w1,
                                                   const float* __restrict__ w2, const float* __restrict__ w3,
                                                   us* __restrict__ o0, us* __restrict__ o1,
                                                   us* __restrict__ o2, us* __restrict__ o3){
    int wsel = blockIdx.x >> 10;
    int i = (blockIdx.x & 1023) * 256 + threadIdx.x;
    const float* src = (wsel == 0) ? w0 : (wsel == 1) ? w1 : (wsel == 2) ? w2 : w3;
    us* dst = (wsel == 0) ? o0 : (wsel == 1) ? o1 : (wsel == 2) ? o2 : o3;
    float4 v = reinterpret_cast<const float4*>(src)[i];
    ushort4 o;
    o.x = f2bf(v.x); o.y = f2bf(v.y); o.z = f2bf(v.z); o.w = f2bf(v.w);
    reinterpret_cast<ushort4*>(dst)[i] = o;
}

#define QSCALE 0.1803368801111244f

#define BAR() __builtin_amdgcn_s_barrier()
#define SGB0() __builtin_amdgcn_sched_barrier(0)
#define LGKM0() do { asm volatile("s_waitcnt lgkmcnt(0)" ::: "memory"); __builtin_amdgcn_sched_barrier(0); } while(0)
#define VMC6() asm volatile("s_waitcnt vmcnt(6)" ::: "memory")
#define VMC4() asm volatile("s_waitcnt vmcnt(4)" ::: "memory")
#define VMC0() asm volatile("s_waitcnt vmcnt(0)" ::: "memory")
#define CFENCE() do { asm volatile("" ::: "memory"); __builtin_amdgcn_sched_barrier(0); } while(0)

// ======================= gemm_qkv4: 256x256 tile, 64x128 waves, single-set compiler-scheduled =======================
// Round-8: keep round-7's geometry (LDS-bytes/FLOP 22.9 -> matrix-pipe-dominant) but FIX the
// register spill: single fragment set (48 VGPR) instead of E/O (96). acc 128 + frags 48 +
// addr ~25 = ~200 < 256 cap. Overlap of ds_read and MFMA is delegated to the compiler, which
// emits counted lgkmcnt between ds_read and dependent MFMA (near-optimal per m97 asm); our
// earlier explicit lgkm0+sched_barrier fences were defeating it. One barrier per K-tile.
// Staging: tile t+1 issued at top of iter t (8 gload_lds), drained by vmcnt(0) at iter end
// (~full-iteration latency cover). WAR safe: all reads of buf[cur] are consumed by MFMAs
// (compiler lgkmcnt => complete) before the barrier; CFENCE after BAR stops hoisting.

#define STAGE_A4(buf, kt) do { \
    _Pragma("unroll") \
    for (int c_ = 0; c_ < 4; c_++) \
        ld_g2l16(Ag + (size_t)(m0 + srow[c_])*1024 + (kt)*64 + sgr[c_]*8, \
                 &smem[(buf)*32768 + (c_*8 + wave)*512]); \
} while(0)

#define STAGE_B4(buf, kt) do { \
    _Pragma("unroll") \
    for (int c_ = 0; c_ < 4; c_++) \
        ld_g2l16(Wb + (size_t)(n0 + srow[c_])*1024 + (kt)*64 + sgr[c_]*8, \
                 &smem[(buf)*32768 + 16384 + (c_*8 + wave)*512]); \
} while(0)

#define LOAD_SET4(buf, KS, AF, BF) do { \
    _Pragma("unroll") \
    for (int i_ = 0; i_ < 4; i_++){ \
        int ra_ = wmm*64 + i_*16 + lane15; \
        int ga_ = ((KS)*4 + quad) ^ (ra_ & 7); \
        AF[i_] = *reinterpret_cast<const short8*>(&smem[(buf)*32768 + ra_*64 + ga_*8]); \
    } \
    _Pragma("unroll") \
    for (int j_ = 0; j_ < 8; j_++){ \
        int rb_ = wnn*128 + j_*16 + lane15; \
        int gb_ = ((KS)*4 + quad) ^ (rb_ & 7); \
        BF[j_] = *reinterpret_cast<const short8*>(&smem[(buf)*32768 + 16384 + rb_*64 + gb_*8]); \
    } \
} while(0)

#define MFMA_SET4(AF, BF) do { \
    __builtin_amdgcn_s_setprio(1); \
    _Pragma("unroll") \
    for (int i_ = 0; i_ < 4; i_++) \
        _Pragma("unroll") \
        for (int j_ = 0; j_ < 8; j_++) \
            acc[i_][j_] = __builtin_amdgcn_mfma_f32_16x16x32_bf16( \
                AF[i_], BF[j_], acc[i_][j_], 0, 0, 0); \
    __builtin_amdgcn_s_setprio(0); \
} while(0)

#define KLOOP4() do { \
    STAGE_A4(0, 0); STAGE_B4(0, 0); \
    VMC0(); BAR(); CFENCE(); \
    _Pragma("unroll 2") \
    for (int t = 0; t < 16; t++){ \
        const int cur = t & 1, nxt = cur ^ 1; \
        if (t < 15){ STAGE_A4(nxt, t + 1); STAGE_B4(nxt, t + 1); } \
        _Pragma("unroll") \
        for (int ks = 0; ks < 2; ks++){ \
            LOAD_SET4(cur, ks, af, bf); \
            MFMA_SET4(af, bf); \
        } \
        if (t < 15) VMC0(); \
        BAR(); CFENCE(); \
    } \
} while(0)

__global__ __launch_bounds__(512, 2) void gemm_qkv4(
    const us* __restrict__ Ag,
    const us* __restrict__ Wqb, const us* __restrict__ Wkb, const us* __restrict__ Wvb,
    const float* __restrict__ bq, const float* __restrict__ bk, const float* __restrict__ bv,
    us* __restrict__ qo, us* __restrict__ ko, us* __restrict__ vto)
{
    __shared__ us smem[65536];   // 2 x (A 16384 us + B 16384 us) = 128 KiB
    const int tid = threadIdx.x;
    const int lane = tid & 63;
    const int wave = tid >> 6;        // 0..7
    const int lane15 = lane & 15;
    const int quad = lane >> 4;
    const int wmm = wave & 3;         // 0..3 (64 rows each)
    const int wnn = wave >> 2;        // 0..1 (128 cols each)
    const int seg = blockIdx.x >> 2;          // 0=Q 1=K 2=V
    const int n0 = (blockIdx.x & 3) * 256;
    const int m0 = blockIdx.y * 256;

    const us* Wb = (seg == 0) ? Wqb : (seg == 1) ? Wkb : Wvb;
    const float* bias = (seg == 0) ? bq : (seg == 1) ? bk : bv;

    int srow[4], sgr[4];
    #pragma unroll
    for (int c = 0; c < 4; c++){
        int s = (c*8 + wave)*64 + lane;
        srow[c] = s >> 3;                       // 0..255
        sgr[c] = (s & 7) ^ ((s >> 3) & 7);
    }

    floatx4 zero = {0.f, 0.f, 0.f, 0.f};
    floatx4 acc[4][8];
    #pragma unroll
    for (int i = 0; i < 4; i++)
        #pragma unroll
        for (int j = 0; j < 8; j++) acc[i][j] = zero;
    short8 af[4], bf[8];

    KLOOP4();

    if (seg < 2){
        #pragma unroll
        for (int i = 0; i < 4; i++){
            #pragma unroll
            for (int j = 0; j < 8; j++){
                int n = n0 + wnn*128 + j*16 + lane15;
                float bvv = bias[n];
                #pragma unroll
                for (int r = 0; r < 4; r++){
                    int m = m0 + wmm*64 + i*16 + quad*4 + r;
                    float val = acc[i][j][r] + bvv;
                    if (seg == 0){
                        qo[(size_t)m*1024 + n] = f2bf(val * QSCALE);
                    } else {
                        int b = m >> 11, tt = m & 2047;
                        int h = n >> 6,  d = n & 63;
                        ko[(((size_t)b*16 + h)*2048 + tt)*64 + d] = f2bf(val);
                    }
                }
            }
        }
    } else {
        // V^T epilogue: 256m x 256n transpose via LDS, two 128-col passes; RL-masked cols zeroed.
        us* lCT = smem;                  // 128*264 = 33792 us <= 65536
        const int b = m0 >> 11;
        const int t0 = m0 & 2047;
        #pragma unroll
        for (int p = 0; p < 2; p++){
            if (p) __syncthreads();
            if (wnn == p){
                #pragma unroll
                for (int j = 0; j < 8; j++){
                    int nl = j*16 + lane15;              // 0..127 within pass
                    float bvv = bias[n0 + p*128 + nl];
                    #pragma unroll
                    for (int i = 0; i < 4; i++){
                        int ml = wmm*64 + i*16 + quad*4; // 0..255
                        unsigned int lo = (unsigned int)f2bf(acc[i][j][0] + bvv) |
                                          ((unsigned int)f2bf(acc[i][j][1] + bvv) << 16);
                        unsigned int hi = (unsigned int)f2bf(acc[i][j][2] + bvv) |
                                          ((unsigned int)f2bf(acc[i][j][3] + bvv) << 16);
                        uint2 pk2; pk2.x = lo; pk2.y = hi;
                        *reinterpret_cast<uint2*>(&lCT[(size_t)nl*264 + ml]) = pk2;
                    }
                }
            }
            __syncthreads();
            int nl = tid >> 2;           // 0..127
            int c4 = tid & 3;            // 64-us segment of the 256-wide row
            int nC = n0 + p*128 + nl;
            int h = nC >> 6, d = nC & 63;
            us* dst = vto + (((size_t)b*16 + h)*64 + d)*2048 + t0 + c4*64;
            int rr = (t0 + c4*64) % 25;
            #pragma unroll
            for (int ii = 0; ii < 8; ii++){
                uint4 v = *reinterpret_cast<const uint4*>(&lCT[(size_t)nl*264 + c4*64 + ii*8]);
                us* pv = reinterpret_cast<us*>(&v);
                #pragma unroll
                for (int e = 0; e < 8; e++){
                    if (rr == 24) pv[e] = 0;
                    rr = (rr == 24) ? 0 : rr + 1;
                }
                *reinterpret_cast<uint4*>(dst + ii*8) = v;
            }
        }
    }
}

// ======================= gemm_out3: exact round-6 proven version (256x128, triple-buffer, E/O) =======================
#define STAGE_A3(buf, kt) do { \
    _Pragma("unroll") \
    for (int c_ = 0; c_ < 4; c_++) \
        ld_g2l16(Ag + (size_t)(m0 + srow[c_])*1024 + (kt)*64 + sgr[c_]*8, \
                 &smem[(buf)*24576 + (c_*8 + wave)*512]); \
} while(0)

#define STAGE_B3(buf, kt) do { \
    _Pragma("unroll") \
    for (int c_ = 0; c_ < 2; c_++) \
        ld_g2l16(Wb + (size_t)(n0 + srow[c_])*1024 + (kt)*64 + sgr[c_]*8, \
                 &smem[(buf)*24576 + 16384 + (c_*8 + wave)*512]); \
} while(0)

#define LOAD_SET3(buf, KS, AF, BF) do { \
    _Pragma("unroll") \
    for (int i_ = 0; i_ < 4; i_++){ \
        int ra_ = wmm*64 + i_*16 + lane15; \
        int ga_ = ((KS)*4 + quad) ^ (ra_ & 7); \
        AF[i_] = *reinterpret_cast<const short8*>(&smem[(buf)*24576 + ra_*64 + ga_*8]); \
    } \
    _Pragma("unroll") \
    for (int j_ = 0; j_ < 4; j_++){ \
        int rb_ = wnn*64 + j_*16 + lane15; \
        int gb_ = ((KS)*4 + quad) ^ (rb_ & 7); \
        BF[j_] = *reinterpret_cast<const short8*>(&smem[(buf)*24576 + 16384 + rb_*64 + gb_*8]); \
    } \
} while(0)

#define MFMA_SET3(AF, BF) do { \
    __builtin_amdgcn_s_setprio(1); \
    _Pragma("unroll") \
    for (int i_ = 0; i_ < 4; i_++) \
        _Pragma("unroll") \
        for (int j_ = 0; j_ < 4; j_++) \
            acc[i_][j_] = __builtin_amdgcn_mfma_f32_16x16x32_bf16( \
                AF[i_], BF[j_], acc[i_][j_], 0, 0, 0); \
    __builtin_amdgcn_s_setprio(0); \
} while(0)

#define KLOOP3() do { \
    STAGE_A3(0, 0); STAGE_B3(0, 0); \
    STAGE_A3(1, 1); STAGE_B3(1, 1); \
    VMC6(); BAR(); \
    LOAD_SET3(0, 0, afE, bfE); LGKM0(); \
    _Pragma("unroll") \
    for (int t = 0; t < 16; t++){ \
        const int cur = t % 3, nxt = (t + 2) % 3, nx1 = (t + 1) % 3; \
        LOAD_SET3(cur, 1, afO, bfO); \
        SGB0(); \
        if (t < 14) STAGE_A3(nxt, t + 2); \
        MFMA_SET3(afE, bfE); \
        LGKM0(); \
        if (t < 14) { VMC4(); } else if (t == 14) { VMC0(); } \
        BAR(); \
        if (t < 15){ LOAD_SET3(nx1, 0, afE, bfE); SGB0(); } \
        if (t < 14) STAGE_B3(nxt, t + 2); \
        MFMA_SET3(afO, bfO); \
        LGKM0(); \
        BAR(); \
    } \
} while(0)

__global__ __launch_bounds__(512, 2) void gemm_out3(
    const us* __restrict__ Ag,
    const us* __restrict__ Wb,
    const float* __restrict__ bias,
    float* __restrict__ out)
{
    __shared__ us smem[73728];
    const int tid = threadIdx.x;
    const int lane = tid & 63;
    const int wave = tid >> 6;
    const int lane15 = lane & 15;
    const int quad = lane >> 4;
    const int wmm = wave & 3;
    const int wnn = wave >> 2;
    const int n0 = blockIdx.x * 128;
    const int m0 = blockIdx.y * 256;

    int srow[4], sgr[4];
    #pragma unroll
    for (int c = 0; c < 4; c++){
        int s = (c*8 + wave)*64 + lane;
        srow[c] = s >> 3;
        sgr[c] = (s & 7) ^ ((s >> 3) & 7);
    }

    floatx4 zero = {0.f, 0.f, 0.f, 0.f};
    floatx4 acc[4][4];
    #pragma unroll
    for (int i = 0; i < 4; i++)
        #pragma unroll
        for (int j = 0; j < 4; j++) acc[i][j] = zero;
    short8 afE[4], bfE[4], afO[4], bfO[4];

    KLOOP3();

    #pragma unroll
    for (int i = 0; i < 4; i++){
        #pragma unroll
        for (int j = 0; j < 4; j++){
            int n = n0 + wnn*64 + j*16 + lane15;
            float bvv = bias[n];
            #pragma unroll
            for (int r = 0; r < 4; r++){
                int m = m0 + wmm*64 + i*16 + quad*4 + r;
                out[(size_t)m*1024 + n] = acc[i][j][r] + bvv;
            }
        }
    }
}

// ---------------- Flash attention v3 (unchanged from round 4) ----------------
__device__ __forceinline__ short8 rdP(const us* pw, int lane15, int ks, int quad){
    const us* a = &pw[lane15*68 + ks*32 + quad*8];
    short4v lo = *reinterpret_cast<const short4v*>(a);
    short4v hi = *reinterpret_cast<const short4v*>(a + 4);
    short8 r = {lo[0], lo[1], lo[2], lo[3], hi[0], hi[1], hi[2], hi[3]};
    return r;
}

__device__ __forceinline__ void pstore_plain(floatx4 (&s)[4], us* pw, int lane15, int quad){
    #pragma unroll
    for (int tj = 0; tj < 4; tj++)
        #pragma unroll
        for (int r = 0; r < 4; r++)
            pw[(quad*4 + r)*68 + tj*16 + lane15] = f2bf(__builtin_amdgcn_exp2f(s[tj][r]));
}

__device__ __forceinline__ void pstore_diag(floatx4 (&s)[4], us* pw, int rgrow, int j0,
                                            int lane15, int quad){
    #pragma unroll
    for (int tj = 0; tj < 4; tj++){
        #pragma unroll
        for (int r = 0; r < 4; r++){
            float p = __builtin_amdgcn_exp2f(s[tj][r]);
            bool kill = (j0 + tj*16 + lane15) > (rgrow + quad*4 + r);
            pw[(quad*4 + r)*68 + tj*16 + lane15] = f2bf(kill ? 0.f : p);
        }
    }
}

#define ATT_STAGE(itn) do { \
    _Pragma("unroll") \
    for (int i_ = 0; i_ < 2; i_++){ \
        ld_g2l16(kb + (size_t)((itn)*64 + srow[i_])*64 + sgr[i_]*8, &lK[(itn) & 1][(i_*4 + wave)*512]); \
        ld_g2l16(vb + (size_t)srow[i_]*2048 + (itn)*64 + sgr[i_]*8, &lV[(itn) & 1][(i_*4 + wave)*512]); \
    } } while(0)

// MODE 0: both rg, no diag. MODE 1: rg0 diag, rg1 plain. MODE 2: rg1 diag, rg0 inactive.
#define ATT_BODY(MODE, ITV) do { \
    const int j0_ = (ITV)*64; \
    __syncthreads(); \
    if ((ITV) + 1 < nIter) ATT_STAGE((ITV) + 1); \
    const us* Kb = lK[(ITV) & 1]; \
    const us* Vb = lV[(ITV) & 1]; \
    floatx4 s0[4], s1[4]; \
    __builtin_amdgcn_s_setprio(1); \
    _Pragma("unroll") \
    for (int tj = 0; tj < 4; tj++){ \
        int rk = tj*16 + lane15; \
        short8 kf0 = *reinterpret_cast<const short8*>(&Kb[rk*64 + ((quad     ^ (rk & 7)))*8]); \
        short8 kf1 = *reinterpret_cast<const short8*>(&Kb[rk*64 + (((4+quad) ^ (rk & 7)))*8]); \
        floatx4 z1 = __builtin_amdgcn_mfma_f32_16x16x32_bf16(qf1a, kf0, zero, 0, 0, 0); \
        s1[tj]     = __builtin_amdgcn_mfma_f32_16x16x32_bf16(qf1b, kf1, z1,   0, 0, 0); \
        if ((MODE) != 2){ \
            floatx4 z0 = __builtin_amdgcn_mfma_f32_16x16x32_bf16(qf0a, kf0, zero, 0, 0, 0); \
            s0[tj]     = __builtin_amdgcn_mfma_f32_16x16x32_bf16(qf0b, kf1, z0,   0, 0, 0); \
        } \
    } \
    __builtin_amdgcn_s_setprio(0); \
    if ((MODE) == 2)      pstore_diag(s1, pw1, rg1, j0_, lane15, quad); \
    else                  pstore_plain(s1, pw1, lane15, quad); \
    if ((MODE) == 1)      pstore_diag(s0, pw0, rg0, j0_, lane15, quad); \
    else if ((MODE) == 0) pstore_plain(s0, pw0, lane15, quad); \
    __builtin_amdgcn_s_setprio(1); \
    _Pragma("unroll") \
    for (int ks = 0; ks < 2; ks++){ \
        short8 mfr = *reinterpret_cast<const short8*>(&lmask[j0_ + ks*32 + quad*8]); \
        short8 pf1 = rdP(pw1, lane15, ks, quad); \
        short8 pf0; \
        lacc1 = __builtin_amdgcn_mfma_f32_16x16x32_bf16(pf1, mfr, lacc1, 0, 0, 0); \
        if ((MODE) != 2){ \
            pf0 = rdP(pw0, lane15, ks, quad); \
            lacc0 = __builtin_amdgcn_mfma_f32_16x16x32_bf16(pf0, mfr, lacc0, 0, 0, 0); \
        } \
        _Pragma("unroll") \
        for (int dt = 0; dt < 4; dt++){ \
            int rv = dt*16 + lane15; \
            short8 vf = *reinterpret_cast<const short8*>(&Vb[rv*64 + (((ks*4+quad) ^ (rv & 7)))*8]); \
            acc1[dt] = __builtin_amdgcn_mfma_f32_16x16x32_bf16(pf1, vf, acc1[dt], 0, 0, 0); \
            if ((MODE) != 2) acc0[dt] = __builtin_amdgcn_mfma_f32_16x16x32_bf16(pf0, vf, acc0[dt], 0, 0, 0); \
        } \
    } \
    __builtin_amdgcn_s_setprio(0); \
} while(0)

__global__ __launch_bounds__(256, 3) void flash_attn(
    const us* __restrict__ q,
    const us* __restrict__ k,
    const us* __restrict__ vT,
    us* __restrict__ y)
{
    __shared__ us lK[2][64*64];        // double-buffered K tile (XOR-swizzled)
    __shared__ us lV[2][64*64];        // double-buffered V^T tile
    __shared__ us lP[4][2][16*68];     // per-wave P buffers (stride 68)
    __shared__ us lmask[2048];         // bf16 column mask: t%25==24 -> 0 else 1
    const int tid = threadIdx.x;
    const int lane = tid & 63;
    const int wave = tid >> 6;
    const int lane15 = lane & 15;
    const int quad = lane >> 4;
    const int lin = blockIdx.x;        // grid 1024 = 16 qtiles x 64 bh, longest-first
    const int qt2 = 15 - (lin >> 6);
    const int bh = lin & 63;
    const int b = bh >> 4, h = bh & 15;
    const int rg0 = qt2*128 + wave*16;
    const int rg1 = rg0 + 64;
    const int nIter = 2*qt2 + 2;

    const us* kb = k  + (size_t)bh*2048*64;
    const us* vb = vT + (size_t)bh*64*2048;

    // build column-mask table (ordered before first use by the loop-head __syncthreads)
    {
        int c0 = tid * 8;
        int rr = c0 % 25;
        ushort4 mv[2];
        us* pm = reinterpret_cast<us*>(mv);
        #pragma unroll
        for (int e = 0; e < 8; e++){
            pm[e] = (rr == 24) ? (us)0 : (us)0x3F80;
            rr = (rr == 24) ? 0 : rr + 1;
        }
        *reinterpret_cast<uint4*>(&lmask[c0]) = *reinterpret_cast<uint4*>(mv);
    }

    floatx4 zero = {0.f, 0.f, 0.f, 0.f};
    us* pw0 = &lP[wave][0][0];
    us* pw1 = &lP[wave][1][0];

    int srow[2], sgr[2];
    #pragma unroll
    for (int i = 0; i < 2; i++){
        int s = (i*4 + wave)*64 + lane;
        srow[i] = s >> 3;
        sgr[i] = (s & 7) ^ ((s >> 3) & 7);
    }

    const us* q0 = q + ((size_t)b*2048 + rg0 + lane15)*1024 + h*64 + quad*8;
    const us* q1 = q + ((size_t)b*2048 + rg1 + lane15)*1024 + h*64 + quad*8;
    short8 qf0a = *reinterpret_cast<const short8*>(q0);
    short8 qf0b = *reinterpret_cast<const short8*>(q0 + 32);
    short8 qf1a = *reinterpret_cast<const short8*>(q1);
    short8 qf1b = *reinterpret_cast<const short8*>(q1 + 32);

    floatx4 acc0[4], acc1[4];
    #pragma unroll
    for (int d = 0; d < 4; d++){ acc0[d] = zero; acc1[d] = zero; }
    floatx4 lacc0 = zero, lacc1 = zero;

    // pre-stage tile 0 into buffer 0
    ATT_STAGE(0);

    int it = 0;
    #pragma unroll 1
    for (; it < nIter - 2; it++) ATT_BODY(0, it);
    ATT_BODY(1, it); it++;
    ATT_BODY(2, it);

    float rl0[4], rl1[4];
    #pragma unroll
    for (int r = 0; r < 4; r++){ rl0[r] = 1.0f / lacc0[r]; rl1[r] = 1.0f / lacc1[r]; }
    #pragma unroll
    for (int dt = 0; dt < 4; dt++){
        #pragma unroll
        for (int r = 0; r < 4; r++){
            int t0 = rg0 + quad*4 + r;
            int t1 = rg1 + quad*4 + r;
            int cc = h*64 + dt*16 + lane15;
            y[((size_t)b*2048 + t0)*1024 + cc] = f2bf(acc0[dt][r] * rl0[r]);
            y[((size_t)b*2048 + t1)*1024 + cc] = f2bf(acc1[dt][r] * rl1[r]);
        }
    }
}

// ---------------- launch ----------------
extern "C" void kernel_launch(void* const* d_in, const int* in_sizes, int n_in,
                              void* d_out, int out_size, void* d_ws, size_t ws_size,
                              hipStream_t stream)
{
    const float* x  = (const float*)d_in[0];
    const float* Wq = (const float*)d_in[1];
    const float* bq = (const float*)d_in[2];
    const float* Wk = (const float*)d_in[3];
    const float* bk = (const float*)d_in[4];
    const float* Wv = (const float*)d_in[5];
    const float* bv = (const float*)d_in[6];
    const float* Wp = (const float*)d_in[7];
    const float* bp = (const float*)d_in[8];
    float* out = (float*)d_out;

    us* ws  = (us*)d_ws;
    us* xbf = ws;                          // [8192,1024]
    us* wqb = xbf + (size_t)8192*1024;
    us* wkb = wqb + (size_t)1024*1024;
    us* wvb = wkb + (size_t)1024*1024;
    us* wpb = wvb + (size_t)1024*1024;
    us* qws = wpb + (size_t)1024*1024;     // q [B,T,C] bf16 (pre-scaled, exp2 domain)
    us* kws = qws + (size_t)8388608;       // k [B,H,T,64]
    us* vtw = kws + (size_t)8388608;       // vT [B,H,64,T] (RL-masked cols zeroed)
    us* yws = vtw + (size_t)8388608;       // y [B,T,C] bf16

    cvt_kernel<<<8192, 256, 0, stream>>>(x, xbf, 2097152);
    cvt4_kernel<<<4096, 256, 0, stream>>>(Wq, Wk, Wv, Wp, wqb, wkb, wvb, wpb);

    gemm_qkv4<<<dim3(12, 32), 512, 0, stream>>>(xbf, wqb, wkb, wvb, bq, bk, bv, qws, kws, vtw);

    flash_attn<<<1024, 256, 0, stream>>>(qws, kws, vtw, yws);

    gemm_out3<<<dim3(8, 32), 512, 0, stream>>>(yws, wpb, bp, out);
}

// Round 9
// 322.507 us; speedup vs baseline: 2.0468x; 1.0091x over previous
//
#include <hip/hip_runtime.h>
#include <hip/hip_bf16.h>

// B=4, T=2048, C=1024, H=16, HD=64. JOINED_DIM=25 (mask col%25==24 -> masked).

typedef __attribute__((ext_vector_type(8))) short short8;
typedef __attribute__((ext_vector_type(4))) short short4v;
typedef __attribute__((ext_vector_type(4))) float floatx4;
typedef unsigned short us;

__device__ __forceinline__ us f2bf(float f){
    union { __hip_bfloat16 h; us u; } cv;
    cv.h = __float2bfloat16(f);
    return cv.u;
}

__device__ __forceinline__ void ld_g2l16(const void* g, void* l){
    __builtin_amdgcn_global_load_lds((const __attribute__((address_space(1))) void*)g,
                                     (__attribute__((address_space(3))) void*)l, 16, 0, 0);
}

// ---------------- fp32 -> bf16 conversion ----------------
__global__ __launch_bounds__(256) void cvt_kernel(const float* __restrict__ in,
                                                  us* __restrict__ out, int n4){
    int i = blockIdx.x * 256 + threadIdx.x;
    if (i < n4){
        float4 v = reinterpret_cast<const float4*>(in)[i];
        ushort4 o;
        o.x = f2bf(v.x); o.y = f2bf(v.y); o.z = f2bf(v.z); o.w = f2bf(v.w);
        reinterpret_cast<ushort4*>(out)[i] = o;
    }
}

__global__ __launch_bounds__(256) void cvt4_kernel(const float* __restrict__ w0, const float* __restrict__ w1,
                                                   const float* __restrict__ w2, const float* __restrict__ w3,
                                                   us* __restrict__ o0, us* __restrict__ o1,
                                                   us* __restrict__ o2, us* __restrict__ o3){
    int wsel = blockIdx.x >> 10;
    int i = (blockIdx.x & 1023) * 256 + threadIdx.x;
    const float* src = (wsel == 0) ? w0 : (wsel == 1) ? w1 : (wsel == 2) ? w2 : w3;
    us* dst = (wsel == 0) ? o0 : (wsel == 1) ? o1 : (wsel == 2) ? o2 : o3;
    float4 v = reinterpret_cast<const float4*>(src)[i];
    ushort4 o;
    o.x = f2bf(v.x); o.y = f2bf(v.y); o.z = f2bf(v.z); o.w = f2bf(v.w);
    reinterpret_cast<ushort4*>(dst)[i] = o;
}

#define QSCALE 0.1803368801111244f

#define BAR() __builtin_amdgcn_s_barrier()
#define SGB0() __builtin_amdgcn_sched_barrier(0)
#define LGKM0() do { asm volatile("s_waitcnt lgkmcnt(0)" ::: "memory"); __builtin_amdgcn_sched_barrier(0); } while(0)
#define VMC6() asm volatile("s_waitcnt vmcnt(6)" ::: "memory")
#define VMC4() asm volatile("s_waitcnt vmcnt(4)" ::: "memory")
#define VMC0() asm volatile("s_waitcnt vmcnt(0)" ::: "memory")
#define CFENCE() do { asm volatile("" ::: "memory"); __builtin_amdgcn_sched_barrier(0); } while(0)

// ======================= gemm_qkv4: 256x256 tile, 64x128 waves, single-set compiler-scheduled =======================
// Round-9: SAME kernel as round 8 except __launch_bounds__(512, 1).
// Evidence (r7/r8): every (512,2) build reports VGPR_Count=128 -> the toolchain resolves the
// 2nd arg as 2 BLOCKS/CU (16 waves/CU = 4 waves/SIMD) -> 128-VGPR cap -> this kernel's ~200
// VGPR demand spilled to scratch (FETCH 110 vs 79 MB, WRITE 77.6 vs 49 MB, MfmaUtil 14%).
// (512,1) -> 1 block/CU (2 waves/SIMD) -> 256-VGPR cap; LDS (128 KiB) already limits
// residency to 1 block/CU, so occupancy is unchanged — only the register cap moves.

#define STAGE_A4(buf, kt) do { \
    _Pragma("unroll") \
    for (int c_ = 0; c_ < 4; c_++) \
        ld_g2l16(Ag + (size_t)(m0 + srow[c_])*1024 + (kt)*64 + sgr[c_]*8, \
                 &smem[(buf)*32768 + (c_*8 + wave)*512]); \
} while(0)

#define STAGE_B4(buf, kt) do { \
    _Pragma("unroll") \
    for (int c_ = 0; c_ < 4; c_++) \
        ld_g2l16(Wb + (size_t)(n0 + srow[c_])*1024 + (kt)*64 + sgr[c_]*8, \
                 &smem[(buf)*32768 + 16384 + (c_*8 + wave)*512]); \
} while(0)

#define LOAD_SET4(buf, KS, AF, BF) do { \
    _Pragma("unroll") \
    for (int i_ = 0; i_ < 4; i_++){ \
        int ra_ = wmm*64 + i_*16 + lane15; \
        int ga_ = ((KS)*4 + quad) ^ (ra_ & 7); \
        AF[i_] = *reinterpret_cast<const short8*>(&smem[(buf)*32768 + ra_*64 + ga_*8]); \
    } \
    _Pragma("unroll") \
    for (int j_ = 0; j_ < 8; j_++){ \
        int rb_ = wnn*128 + j_*16 + lane15; \
        int gb_ = ((KS)*4 + quad) ^ (rb_ & 7); \
        BF[j_] = *reinterpret_cast<const short8*>(&smem[(buf)*32768 + 16384 + rb_*64 + gb_*8]); \
    } \
} while(0)

#define MFMA_SET4(AF, BF) do { \
    __builtin_amdgcn_s_setprio(1); \
    _Pragma("unroll") \
    for (int i_ = 0; i_ < 4; i_++) \
        _Pragma("unroll") \
        for (int j_ = 0; j_ < 8; j_++) \
            acc[i_][j_] = __builtin_amdgcn_mfma_f32_16x16x32_bf16( \
                AF[i_], BF[j_], acc[i_][j_], 0, 0, 0); \
    __builtin_amdgcn_s_setprio(0); \
} while(0)

#define KLOOP4() do { \
    STAGE_A4(0, 0); STAGE_B4(0, 0); \
    VMC0(); BAR(); CFENCE(); \
    _Pragma("unroll 2") \
    for (int t = 0; t < 16; t++){ \
        const int cur = t & 1, nxt = cur ^ 1; \
        if (t < 15){ STAGE_A4(nxt, t + 1); STAGE_B4(nxt, t + 1); } \
        _Pragma("unroll") \
        for (int ks = 0; ks < 2; ks++){ \
            LOAD_SET4(cur, ks, af, bf); \
            MFMA_SET4(af, bf); \
        } \
        if (t < 15) VMC0(); \
        BAR(); CFENCE(); \
    } \
} while(0)

__global__ __launch_bounds__(512, 1) void gemm_qkv4(
    const us* __restrict__ Ag,
    const us* __restrict__ Wqb, const us* __restrict__ Wkb, const us* __restrict__ Wvb,
    const float* __restrict__ bq, const float* __restrict__ bk, const float* __restrict__ bv,
    us* __restrict__ qo, us* __restrict__ ko, us* __restrict__ vto)
{
    __shared__ us smem[65536];   // 2 x (A 16384 us + B 16384 us) = 128 KiB
    const int tid = threadIdx.x;
    const int lane = tid & 63;
    const int wave = tid >> 6;        // 0..7
    const int lane15 = lane & 15;
    const int quad = lane >> 4;
    const int wmm = wave & 3;         // 0..3 (64 rows each)
    const int wnn = wave >> 2;        // 0..1 (128 cols each)
    const int seg = blockIdx.x >> 2;          // 0=Q 1=K 2=V
    const int n0 = (blockIdx.x & 3) * 256;
    const int m0 = blockIdx.y * 256;

    const us* Wb = (seg == 0) ? Wqb : (seg == 1) ? Wkb : Wvb;
    const float* bias = (seg == 0) ? bq : (seg == 1) ? bk : bv;

    int srow[4], sgr[4];
    #pragma unroll
    for (int c = 0; c < 4; c++){
        int s = (c*8 + wave)*64 + lane;
        srow[c] = s >> 3;                       // 0..255
        sgr[c] = (s & 7) ^ ((s >> 3) & 7);
    }

    floatx4 zero = {0.f, 0.f, 0.f, 0.f};
    floatx4 acc[4][8];
    #pragma unroll
    for (int i = 0; i < 4; i++)
        #pragma unroll
        for (int j = 0; j < 8; j++) acc[i][j] = zero;
    short8 af[4], bf[8];

    KLOOP4();

    if (seg < 2){
        #pragma unroll
        for (int i = 0; i < 4; i++){
            #pragma unroll
            for (int j = 0; j < 8; j++){
                int n = n0 + wnn*128 + j*16 + lane15;
                float bvv = bias[n];
                #pragma unroll
                for (int r = 0; r < 4; r++){
                    int m = m0 + wmm*64 + i*16 + quad*4 + r;
                    float val = acc[i][j][r] + bvv;
                    if (seg == 0){
                        qo[(size_t)m*1024 + n] = f2bf(val * QSCALE);
                    } else {
                        int b = m >> 11, tt = m & 2047;
                        int h = n >> 6,  d = n & 63;
                        ko[(((size_t)b*16 + h)*2048 + tt)*64 + d] = f2bf(val);
                    }
                }
            }
        }
    } else {
        // V^T epilogue: 256m x 256n transpose via LDS, two 128-col passes; RL-masked cols zeroed.
        us* lCT = smem;                  // 128*264 = 33792 us <= 65536
        const int b = m0 >> 11;
        const int t0 = m0 & 2047;
        #pragma unroll
        for (int p = 0; p < 2; p++){
            if (p) __syncthreads();
            if (wnn == p){
                #pragma unroll
                for (int j = 0; j < 8; j++){
                    int nl = j*16 + lane15;              // 0..127 within pass
                    float bvv = bias[n0 + p*128 + nl];
                    #pragma unroll
                    for (int i = 0; i < 4; i++){
                        int ml = wmm*64 + i*16 + quad*4; // 0..255
                        unsigned int lo = (unsigned int)f2bf(acc[i][j][0] + bvv) |
                                          ((unsigned int)f2bf(acc[i][j][1] + bvv) << 16);
                        unsigned int hi = (unsigned int)f2bf(acc[i][j][2] + bvv) |
                                          ((unsigned int)f2bf(acc[i][j][3] + bvv) << 16);
                        uint2 pk2; pk2.x = lo; pk2.y = hi;
                        *reinterpret_cast<uint2*>(&lCT[(size_t)nl*264 + ml]) = pk2;
                    }
                }
            }
            __syncthreads();
            int nl = tid >> 2;           // 0..127
            int c4 = tid & 3;            // 64-us segment of the 256-wide row
            int nC = n0 + p*128 + nl;
            int h = nC >> 6, d = nC & 63;
            us* dst = vto + (((size_t)b*16 + h)*64 + d)*2048 + t0 + c4*64;
            int rr = (t0 + c4*64) % 25;
            #pragma unroll
            for (int ii = 0; ii < 8; ii++){
                uint4 v = *reinterpret_cast<const uint4*>(&lCT[(size_t)nl*264 + c4*64 + ii*8]);
                us* pv = reinterpret_cast<us*>(&v);
                #pragma unroll
                for (int e = 0; e < 8; e++){
                    if (rr == 24) pv[e] = 0;
                    rr = (rr == 24) ? 0 : rr + 1;
                }
                *reinterpret_cast<uint4*>(dst + ii*8) = v;
            }
        }
    }
}

// ======================= gemm_out3: exact round-6 proven version (256x128, triple-buffer, E/O) =======================
#define STAGE_A3(buf, kt) do { \
    _Pragma("unroll") \
    for (int c_ = 0; c_ < 4; c_++) \
        ld_g2l16(Ag + (size_t)(m0 + srow[c_])*1024 + (kt)*64 + sgr[c_]*8, \
                 &smem[(buf)*24576 + (c_*8 + wave)*512]); \
} while(0)

#define STAGE_B3(buf, kt) do { \
    _Pragma("unroll") \
    for (int c_ = 0; c_ < 2; c_++) \
        ld_g2l16(Wb + (size_t)(n0 + srow[c_])*1024 + (kt)*64 + sgr[c_]*8, \
                 &smem[(buf)*24576 + 16384 + (c_*8 + wave)*512]); \
} while(0)

#define LOAD_SET3(buf, KS, AF, BF) do { \
    _Pragma("unroll") \
    for (int i_ = 0; i_ < 4; i_++){ \
        int ra_ = wmm*64 + i_*16 + lane15; \
        int ga_ = ((KS)*4 + quad) ^ (ra_ & 7); \
        AF[i_] = *reinterpret_cast<const short8*>(&smem[(buf)*24576 + ra_*64 + ga_*8]); \
    } \
    _Pragma("unroll") \
    for (int j_ = 0; j_ < 4; j_++){ \
        int rb_ = wnn*64 + j_*16 + lane15; \
        int gb_ = ((KS)*4 + quad) ^ (rb_ & 7); \
        BF[j_] = *reinterpret_cast<const short8*>(&smem[(buf)*24576 + 16384 + rb_*64 + gb_*8]); \
    } \
} while(0)

#define MFMA_SET3(AF, BF) do { \
    __builtin_amdgcn_s_setprio(1); \
    _Pragma("unroll") \
    for (int i_ = 0; i_ < 4; i_++) \
        _Pragma("unroll") \
        for (int j_ = 0; j_ < 4; j_++) \
            acc[i_][j_] = __builtin_amdgcn_mfma_f32_16x16x32_bf16( \
                AF[i_], BF[j_], acc[i_][j_], 0, 0, 0); \
    __builtin_amdgcn_s_setprio(0); \
} while(0)

#define KLOOP3() do { \
    STAGE_A3(0, 0); STAGE_B3(0, 0); \
    STAGE_A3(1, 1); STAGE_B3(1, 1); \
    VMC6(); BAR(); \
    LOAD_SET3(0, 0, afE, bfE); LGKM0(); \
    _Pragma("unroll") \
    for (int t = 0; t < 16; t++){ \
        const int cur = t % 3, nxt = (t + 2) % 3, nx1 = (t + 1) % 3; \
        LOAD_SET3(cur, 1, afO, bfO); \
        SGB0(); \
        if (t < 14) STAGE_A3(nxt, t + 2); \
        MFMA_SET3(afE, bfE); \
        LGKM0(); \
        if (t < 14) { VMC4(); } else if (t == 14) { VMC0(); } \
        BAR(); \
        if (t < 15){ LOAD_SET3(nx1, 0, afE, bfE); SGB0(); } \
        if (t < 14) STAGE_B3(nxt, t + 2); \
        MFMA_SET3(afO, bfO); \
        LGKM0(); \
        BAR(); \
    } \
} while(0)

__global__ __launch_bounds__(512, 2) void gemm_out3(
    const us* __restrict__ Ag,
    const us* __restrict__ Wb,
    const float* __restrict__ bias,
    float* __restrict__ out)
{
    __shared__ us smem[73728];
    const int tid = threadIdx.x;
    const int lane = tid & 63;
    const int wave = tid >> 6;
    const int lane15 = lane & 15;
    const int quad = lane >> 4;
    const int wmm = wave & 3;
    const int wnn = wave >> 2;
    const int n0 = blockIdx.x * 128;
    const int m0 = blockIdx.y * 256;

    int srow[4], sgr[4];
    #pragma unroll
    for (int c = 0; c < 4; c++){
        int s = (c*8 + wave)*64 + lane;
        srow[c] = s >> 3;
        sgr[c] = (s & 7) ^ ((s >> 3) & 7);
    }

    floatx4 zero = {0.f, 0.f, 0.f, 0.f};
    floatx4 acc[4][4];
    #pragma unroll
    for (int i = 0; i < 4; i++)
        #pragma unroll
        for (int j = 0; j < 4; j++) acc[i][j] = zero;
    short8 afE[4], bfE[4], afO[4], bfO[4];

    KLOOP3();

    #pragma unroll
    for (int i = 0; i < 4; i++){
        #pragma unroll
        for (int j = 0; j < 4; j++){
            int n = n0 + wnn*64 + j*16 + lane15;
            float bvv = bias[n];
            #pragma unroll
            for (int r = 0; r < 4; r++){
                int m = m0 + wmm*64 + i*16 + quad*4 + r;
                out[(size_t)m*1024 + n] = acc[i][j][r] + bvv;
            }
        }
    }
}

// ---------------- Flash attention v3 (unchanged from round 4) ----------------
__device__ __forceinline__ short8 rdP(const us* pw, int lane15, int ks, int quad){
    const us* a = &pw[lane15*68 + ks*32 + quad*8];
    short4v lo = *reinterpret_cast<const short4v*>(a);
    short4v hi = *reinterpret_cast<const short4v*>(a + 4);
    short8 r = {lo[0], lo[1], lo[2], lo[3], hi[0], hi[1], hi[2], hi[3]};
    return r;
}

__device__ __forceinline__ void pstore_plain(floatx4 (&s)[4], us* pw, int lane15, int quad){
    #pragma unroll
    for (int tj = 0; tj < 4; tj++)
        #pragma unroll
        for (int r = 0; r < 4; r++)
            pw[(quad*4 + r)*68 + tj*16 + lane15] = f2bf(__builtin_amdgcn_exp2f(s[tj][r]));
}

__device__ __forceinline__ void pstore_diag(floatx4 (&s)[4], us* pw, int rgrow, int j0,
                                            int lane15, int quad){
    #pragma unroll
    for (int tj = 0; tj < 4; tj++){
        #pragma unroll
        for (int r = 0; r < 4; r++){
            float p = __builtin_amdgcn_exp2f(s[tj][r]);
            bool kill = (j0 + tj*16 + lane15) > (rgrow + quad*4 + r);
            pw[(quad*4 + r)*68 + tj*16 + lane15] = f2bf(kill ? 0.f : p);
        }
    }
}

#define ATT_STAGE(itn) do { \
    _Pragma("unroll") \
    for (int i_ = 0; i_ < 2; i_++){ \
        ld_g2l16(kb + (size_t)((itn)*64 + srow[i_])*64 + sgr[i_]*8, &lK[(itn) & 1][(i_*4 + wave)*512]); \
        ld_g2l16(vb + (size_t)srow[i_]*2048 + (itn)*64 + sgr[i_]*8, &lV[(itn) & 1][(i_*4 + wave)*512]); \
    } } while(0)

// MODE 0: both rg, no diag. MODE 1: rg0 diag, rg1 plain. MODE 2: rg1 diag, rg0 inactive.
#define ATT_BODY(MODE, ITV) do { \
    const int j0_ = (ITV)*64; \
    __syncthreads(); \
    if ((ITV) + 1 < nIter) ATT_STAGE((ITV) + 1); \
    const us* Kb = lK[(ITV) & 1]; \
    const us* Vb = lV[(ITV) & 1]; \
    floatx4 s0[4], s1[4]; \
    __builtin_amdgcn_s_setprio(1); \
    _Pragma("unroll") \
    for (int tj = 0; tj < 4; tj++){ \
        int rk = tj*16 + lane15; \
        short8 kf0 = *reinterpret_cast<const short8*>(&Kb[rk*64 + ((quad     ^ (rk & 7)))*8]); \
        short8 kf1 = *reinterpret_cast<const short8*>(&Kb[rk*64 + (((4+quad) ^ (rk & 7)))*8]); \
        floatx4 z1 = __builtin_amdgcn_mfma_f32_16x16x32_bf16(qf1a, kf0, zero, 0, 0, 0); \
        s1[tj]     = __builtin_amdgcn_mfma_f32_16x16x32_bf16(qf1b, kf1, z1,   0, 0, 0); \
        if ((MODE) != 2){ \
            floatx4 z0 = __builtin_amdgcn_mfma_f32_16x16x32_bf16(qf0a, kf0, zero, 0, 0, 0); \
            s0[tj]     = __builtin_amdgcn_mfma_f32_16x16x32_bf16(qf0b, kf1, z0,   0, 0, 0); \
        } \
    } \
    __builtin_amdgcn_s_setprio(0); \
    if ((MODE) == 2)      pstore_diag(s1, pw1, rg1, j0_, lane15, quad); \
    else                  pstore_plain(s1, pw1, lane15, quad); \
    if ((MODE) == 1)      pstore_diag(s0, pw0, rg0, j0_, lane15, quad); \
    else if ((MODE) == 0) pstore_plain(s0, pw0, lane15, quad); \
    __builtin_amdgcn_s_setprio(1); \
    _Pragma("unroll") \
    for (int ks = 0; ks < 2; ks++){ \
        short8 mfr = *reinterpret_cast<const short8*>(&lmask[j0_ + ks*32 + quad*8]); \
        short8 pf1 = rdP(pw1, lane15, ks, quad); \
        short8 pf0; \
        lacc1 = __builtin_amdgcn_mfma_f32_16x16x32_bf16(pf1, mfr, lacc1, 0, 0, 0); \
        if ((MODE) != 2){ \
            pf0 = rdP(pw0, lane15, ks, quad); \
            lacc0 = __builtin_amdgcn_mfma_f32_16x16x32_bf16(pf0, mfr, lacc0, 0, 0, 0); \
        } \
        _Pragma("unroll") \
        for (int dt = 0; dt < 4; dt++){ \
            int rv = dt*16 + lane15; \
            short8 vf = *reinterpret_cast<const short8*>(&Vb[rv*64 + (((ks*4+quad) ^ (rv & 7)))*8]); \
            acc1[dt] = __builtin_amdgcn_mfma_f32_16x16x32_bf16(pf1, vf, acc1[dt], 0, 0, 0); \
            if ((MODE) != 2) acc0[dt] = __builtin_amdgcn_mfma_f32_16x16x32_bf16(pf0, vf, acc0[dt], 0, 0, 0); \
        } \
    } \
    __builtin_amdgcn_s_setprio(0); \
} while(0)

__global__ __launch_bounds__(256, 3) void flash_attn(
    const us* __restrict__ q,
    const us* __restrict__ k,
    const us* __restrict__ vT,
    us* __restrict__ y)
{
    __shared__ us lK[2][64*64];        // double-buffered K tile (XOR-swizzled)
    __shared__ us lV[2][64*64];        // double-buffered V^T tile
    __shared__ us lP[4][2][16*68];     // per-wave P buffers (stride 68)
    __shared__ us lmask[2048];         // bf16 column mask: t%25==24 -> 0 else 1
    const int tid = threadIdx.x;
    const int lane = tid & 63;
    const int wave = tid >> 6;
    const int lane15 = lane & 15;
    const int quad = lane >> 4;
    const int lin = blockIdx.x;        // grid 1024 = 16 qtiles x 64 bh, longest-first
    const int qt2 = 15 - (lin >> 6);
    const int bh = lin & 63;
    const int b = bh >> 4, h = bh & 15;
    const int rg0 = qt2*128 + wave*16;
    const int rg1 = rg0 + 64;
    const int nIter = 2*qt2 + 2;

    const us* kb = k  + (size_t)bh*2048*64;
    const us* vb = vT + (size_t)bh*64*2048;

    // build column-mask table (ordered before first use by the loop-head __syncthreads)
    {
        int c0 = tid * 8;
        int rr = c0 % 25;
        ushort4 mv[2];
        us* pm = reinterpret_cast<us*>(mv);
        #pragma unroll
        for (int e = 0; e < 8; e++){
            pm[e] = (rr == 24) ? (us)0 : (us)0x3F80;
            rr = (rr == 24) ? 0 : rr + 1;
        }
        *reinterpret_cast<uint4*>(&lmask[c0]) = *reinterpret_cast<uint4*>(mv);
    }

    floatx4 zero = {0.f, 0.f, 0.f, 0.f};
    us* pw0 = &lP[wave][0][0];
    us* pw1 = &lP[wave][1][0];

    int srow[2], sgr[2];
    #pragma unroll
    for (int i = 0; i < 2; i++){
        int s = (i*4 + wave)*64 + lane;
        srow[i] = s >> 3;
        sgr[i] = (s & 7) ^ ((s >> 3) & 7);
    }

    const us* q0 = q + ((size_t)b*2048 + rg0 + lane15)*1024 + h*64 + quad*8;
    const us* q1 = q + ((size_t)b*2048 + rg1 + lane15)*1024 + h*64 + quad*8;
    short8 qf0a = *reinterpret_cast<const short8*>(q0);
    short8 qf0b = *reinterpret_cast<const short8*>(q0 + 32);
    short8 qf1a = *reinterpret_cast<const short8*>(q1);
    short8 qf1b = *reinterpret_cast<const short8*>(q1 + 32);

    floatx4 acc0[4], acc1[4];
    #pragma unroll
    for (int d = 0; d < 4; d++){ acc0[d] = zero; acc1[d] = zero; }
    floatx4 lacc0 = zero, lacc1 = zero;

    // pre-stage tile 0 into buffer 0
    ATT_STAGE(0);

    int it = 0;
    #pragma unroll 1
    for (; it < nIter - 2; it++) ATT_BODY(0, it);
    ATT_BODY(1, it); it++;
    ATT_BODY(2, it);

    float rl0[4], rl1[4];
    #pragma unroll
    for (int r = 0; r < 4; r++){ rl0[r] = 1.0f / lacc0[r]; rl1[r] = 1.0f / lacc1[r]; }
    #pragma unroll
    for (int dt = 0; dt < 4; dt++){
        #pragma unroll
        for (int r = 0; r < 4; r++){
            int t0 = rg0 + quad*4 + r;
            int t1 = rg1 + quad*4 + r;
            int cc = h*64 + dt*16 + lane15;
            y[((size_t)b*2048 + t0)*1024 + cc] = f2bf(acc0[dt][r] * rl0[r]);
            y[((size_t)b*2048 + t1)*1024 + cc] = f2bf(acc1[dt][r] * rl1[r]);
        }
    }
}

// ---------------- launch ----------------
extern "C" void kernel_launch(void* const* d_in, const int* in_sizes, int n_in,
                              void* d_out, int out_size, void* d_ws, size_t ws_size,
                              hipStream_t stream)
{
    const float* x  = (const float*)d_in[0];
    const float* Wq = (const float*)d_in[1];
    const float* bq = (const float*)d_in[2];
    const float* Wk = (const float*)d_in[3];
    const float* bk = (const float*)d_in[4];
    const float* Wv = (const float*)d_in[5];
    const float* bv = (const float*)d_in[6];
    const float* Wp = (const float*)d_in[7];
    const float* bp = (const float*)d_in[8];
    float* out = (float*)d_out;

    us* ws  = (us*)d_ws;
    us* xbf = ws;                          // [8192,1024]
    us* wqb = xbf + (size_t)8192*1024;
    us* wkb = wqb + (size_t)1024*1024;
    us* wvb = wkb + (size_t)1024*1024;
    us* wpb = wvb + (size_t)1024*1024;
    us* qws = wpb + (size_t)1024*1024;     // q [B,T,C] bf16 (pre-scaled, exp2 domain)
    us* kws = qws + (size_t)8388608;       // k [B,H,T,64]
    us* vtw = kws + (size_t)8388608;       // vT [B,H,64,T] (RL-masked cols zeroed)
    us* yws = vtw + (size_t)8388608;       // y [B,T,C] bf16

    cvt_kernel<<<8192, 256, 0, stream>>>(x, xbf, 2097152);
    cvt4_kernel<<<4096, 256, 0, stream>>>(Wq, Wk, Wv, Wp, wqb, wkb, wvb, wpb);

    gemm_qkv4<<<dim3(12, 32), 512, 0, stream>>>(xbf, wqb, wkb, wvb, bq, bk, bv, qws, kws, vtw);

    flash_attn<<<1024, 256, 0, stream>>>(qws, kws, vtw, yws);

    gemm_out3<<<dim3(8, 32), 512, 0, stream>>>(yws, wpb, bp, out);
}

// Round 10
// 254.140 us; speedup vs baseline: 2.5974x; 1.2690x over previous
//
#include <hip/hip_runtime.h>
#include <hip/hip_bf16.h>

// B=4, T=2048, C=1024, H=16, HD=64. JOINED_DIM=25 (mask col%25==24 -> masked).

typedef __attribute__((ext_vector_type(8))) short short8;
typedef __attribute__((ext_vector_type(4))) short short4v;
typedef __attribute__((ext_vector_type(4))) float floatx4;
typedef unsigned short us;

__device__ __forceinline__ us f2bf(float f){
    union { __hip_bfloat16 h; us u; } cv;
    cv.h = __float2bfloat16(f);
    return cv.u;
}

__device__ __forceinline__ void ld_g2l16(const void* g, void* l){
    __builtin_amdgcn_global_load_lds((const __attribute__((address_space(1))) void*)g,
                                     (__attribute__((address_space(3))) void*)l, 16, 0, 0);
}

// ---------------- fp32 -> bf16 conversion ----------------
__global__ __launch_bounds__(256) void cvt_kernel(const float* __restrict__ in,
                                                  us* __restrict__ out, int n4){
    int i = blockIdx.x * 256 + threadIdx.x;
    if (i < n4){
        float4 v = reinterpret_cast<const float4*>(in)[i];
        ushort4 o;
        o.x = f2bf(v.x); o.y = f2bf(v.y); o.z = f2bf(v.z); o.w = f2bf(v.w);
        reinterpret_cast<ushort4*>(out)[i] = o;
    }
}

__global__ __launch_bounds__(256) void cvt4_kernel(const float* __restrict__ w0, const float* __restrict__ w1,
                                                   const float* __restrict__ w2, const float* __restrict__ w3,
                                                   us* __restrict__ o0, us* __restrict__ o1,
                                                   us* __restrict__ o2, us* __restrict__ o3){
    int wsel = blockIdx.x >> 10;
    int i = (blockIdx.x & 1023) * 256 + threadIdx.x;
    const float* src = (wsel == 0) ? w0 : (wsel == 1) ? w1 : (wsel == 2) ? w2 : w3;
    us* dst = (wsel == 0) ? o0 : (wsel == 1) ? o1 : (wsel == 2) ? o2 : o3;
    float4 v = reinterpret_cast<const float4*>(src)[i];
    ushort4 o;
    o.x = f2bf(v.x); o.y = f2bf(v.y); o.z = f2bf(v.z); o.w = f2bf(v.w);
    reinterpret_cast<ushort4*>(dst)[i] = o;
}

#define QSCALE 0.1803368801111244f

#define BAR() __builtin_amdgcn_s_barrier()
#define SGB0() __builtin_amdgcn_sched_barrier(0)
#define LGKM0() do { asm volatile("s_waitcnt lgkmcnt(0)" ::: "memory"); __builtin_amdgcn_sched_barrier(0); } while(0)
#define VMC12() asm volatile("s_waitcnt vmcnt(12)" ::: "memory")
#define VMC6() asm volatile("s_waitcnt vmcnt(6)" ::: "memory")
#define VMC4() asm volatile("s_waitcnt vmcnt(4)" ::: "memory")
#define VMC0() asm volatile("s_waitcnt vmcnt(0)" ::: "memory")

// ======================= gemm_qkv5: 128x256 tile, 4 waves (64x128 each), tri-buffer + E/O =======================
// Round-10: same MFMA-dominant geometry (wave 64x128, LDS-read 1129 < MFMA 1242 cyc/K-tile/CU)
// but 256-thread blocks -> 1 block/CU -> 1 wave/SIMD -> 512-reg/wave budget (vs 256 at 8-wave
// blocks, which forced the r7-r9 spill). E/O register read-ahead provides the ILP that TLP no
// longer does; one wave per SIMD can saturate the matrix pipe (issue ~4 cyc << pipe ~19 cyc).
// LDS: 3 buffers x (A 128x64 16KB + B 256x64 32KB) = 144 KiB. 12 gload_lds/thread/K-tile.
// Choreography (R6-proven, re-derived): P1(t): readO(cur,ks1) | stage A(t+2) | MFMA(E) |
// lgkm0 | vmcnt(4) | bar;  P2(t): readE(t+1,ks0) | stage B(t+2) | MFMA(O) | lgkm0 | bar.
// vmcnt(4)@P1: outstanding <= A(t+1)4 + B(t+1)8 + A(t+2)4; drain to 4 leaves A(t+2) ->
// tile t+1 complete before P2 reads it. WAR: buf (t+2)%3's last reads are P1(t-1)'s O-set,
// lgkm-drained before that barrier. Grid 12x64 = 768 = 3 exact CU rounds.

#define STAGE_A5(buf, kt) do { \
    _Pragma("unroll") \
    for (int c_ = 0; c_ < 4; c_++) \
        ld_g2l16(Ag + (size_t)(m0 + srow[c_])*1024 + (kt)*64 + sgr[c_]*8, \
                 &smem[(buf)*24576 + (c_*4 + wave)*512]); \
} while(0)

#define STAGE_B5(buf, kt) do { \
    _Pragma("unroll") \
    for (int c_ = 0; c_ < 8; c_++) \
        ld_g2l16(Wb + (size_t)(n0 + srow[c_])*1024 + (kt)*64 + sgr[c_]*8, \
                 &smem[(buf)*24576 + 8192 + (c_*4 + wave)*512]); \
} while(0)

#define LOAD_SET5(buf, KS, AF, BF) do { \
    _Pragma("unroll") \
    for (int i_ = 0; i_ < 4; i_++){ \
        int ra_ = wmm*64 + i_*16 + lane15; \
        int ga_ = ((KS)*4 + quad) ^ (ra_ & 7); \
        AF[i_] = *reinterpret_cast<const short8*>(&smem[(buf)*24576 + ra_*64 + ga_*8]); \
    } \
    _Pragma("unroll") \
    for (int j_ = 0; j_ < 8; j_++){ \
        int rb_ = wnn*128 + j_*16 + lane15; \
        int gb_ = ((KS)*4 + quad) ^ (rb_ & 7); \
        BF[j_] = *reinterpret_cast<const short8*>(&smem[(buf)*24576 + 8192 + rb_*64 + gb_*8]); \
    } \
} while(0)

#define MFMA_SET5(AF, BF) do { \
    __builtin_amdgcn_s_setprio(1); \
    _Pragma("unroll") \
    for (int i_ = 0; i_ < 4; i_++) \
        _Pragma("unroll") \
        for (int j_ = 0; j_ < 8; j_++) \
            acc[i_][j_] = __builtin_amdgcn_mfma_f32_16x16x32_bf16( \
                AF[i_], BF[j_], acc[i_][j_], 0, 0, 0); \
    __builtin_amdgcn_s_setprio(0); \
} while(0)

#define KLOOP5() do { \
    STAGE_A5(0, 0); STAGE_B5(0, 0); \
    STAGE_A5(1, 1); STAGE_B5(1, 1); \
    VMC12(); BAR(); \
    LOAD_SET5(0, 0, afE, bfE); LGKM0(); \
    _Pragma("unroll") \
    for (int t = 0; t < 16; t++){ \
        const int cur = t % 3, nxt = (t + 2) % 3, nx1 = (t + 1) % 3; \
        LOAD_SET5(cur, 1, afO, bfO); \
        SGB0(); \
        if (t < 14) STAGE_A5(nxt, t + 2); \
        MFMA_SET5(afE, bfE); \
        LGKM0(); \
        if (t < 14) { VMC4(); } else if (t == 14) { VMC0(); } \
        BAR(); \
        if (t < 15){ LOAD_SET5(nx1, 0, afE, bfE); SGB0(); } \
        if (t < 14) STAGE_B5(nxt, t + 2); \
        MFMA_SET5(afO, bfO); \
        LGKM0(); \
        BAR(); \
    } \
} while(0)

__global__ __launch_bounds__(256) void gemm_qkv5(
    const us* __restrict__ Ag,
    const us* __restrict__ Wqb, const us* __restrict__ Wkb, const us* __restrict__ Wvb,
    const float* __restrict__ bq, const float* __restrict__ bk, const float* __restrict__ bv,
    us* __restrict__ qo, us* __restrict__ ko, us* __restrict__ vto)
{
    __shared__ us smem[73728];   // 3 x (A 8192 us + B 16384 us) = 144 KiB
    const int tid = threadIdx.x;
    const int lane = tid & 63;
    const int wave = tid >> 6;        // 0..3
    const int lane15 = lane & 15;
    const int quad = lane >> 4;
    const int wmm = wave >> 1;        // 0..1 (64 rows each of 128)
    const int wnn = wave & 1;         // 0..1 (128 cols each of 256)
    const int seg = blockIdx.x >> 2;          // 0=Q 1=K 2=V
    const int n0 = (blockIdx.x & 3) * 256;
    const int m0 = blockIdx.y * 128;

    const us* Wb = (seg == 0) ? Wqb : (seg == 1) ? Wkb : Wvb;
    const float* bias = (seg == 0) ? bq : (seg == 1) ? bk : bv;

    int srow[8], sgr[8];
    #pragma unroll
    for (int c = 0; c < 8; c++){
        int s = (c*4 + wave)*64 + lane;
        srow[c] = s >> 3;                 // A uses c<4 (rows 0..127), B uses c<8 (rows 0..255)
        sgr[c] = (s & 7) ^ ((s >> 3) & 7);
    }

    floatx4 zero = {0.f, 0.f, 0.f, 0.f};
    floatx4 acc[4][8];
    #pragma unroll
    for (int i = 0; i < 4; i++)
        #pragma unroll
        for (int j = 0; j < 8; j++) acc[i][j] = zero;
    short8 afE[4], bfE[8], afO[4], bfO[8];

    KLOOP5();

    if (seg < 2){
        #pragma unroll
        for (int i = 0; i < 4; i++){
            #pragma unroll
            for (int j = 0; j < 8; j++){
                int n = n0 + wnn*128 + j*16 + lane15;
                float bvv = bias[n];
                #pragma unroll
                for (int r = 0; r < 4; r++){
                    int m = m0 + wmm*64 + i*16 + quad*4 + r;
                    float val = acc[i][j][r] + bvv;
                    if (seg == 0){
                        qo[(size_t)m*1024 + n] = f2bf(val * QSCALE);
                    } else {
                        int b = m >> 11, tt = m & 2047;
                        int h = n >> 6,  d = n & 63;
                        ko[(((size_t)b*16 + h)*2048 + tt)*64 + d] = f2bf(val);
                    }
                }
            }
        }
    } else {
        // V^T epilogue: 128m x 256n transpose via LDS [256 n][136 us]; RL cols (t%25==24) zeroed.
        us* lCT = smem;                  // 256*136 = 34816 us <= 73728
        const int b = m0 >> 11;
        const int t0 = m0 & 2047;
        #pragma unroll
        for (int j = 0; j < 8; j++){
            int nl = wnn*128 + j*16 + lane15;        // 0..255
            float bvv = bias[n0 + nl];
            #pragma unroll
            for (int i = 0; i < 4; i++){
                int ml = wmm*64 + i*16 + quad*4;     // 0..127
                unsigned int lo = (unsigned int)f2bf(acc[i][j][0] + bvv) |
                                  ((unsigned int)f2bf(acc[i][j][1] + bvv) << 16);
                unsigned int hi = (unsigned int)f2bf(acc[i][j][2] + bvv) |
                                  ((unsigned int)f2bf(acc[i][j][3] + bvv) << 16);
                uint2 pk2; pk2.x = lo; pk2.y = hi;
                *reinterpret_cast<uint2*>(&lCT[(size_t)nl*136 + ml]) = pk2;
            }
        }
        __syncthreads();
        int nC = n0 + tid;                           // one column per thread
        int h = nC >> 6, d = nC & 63;
        us* dst = vto + (((size_t)b*16 + h)*64 + d)*2048 + t0;
        int rr = t0 % 25;
        #pragma unroll
        for (int ii = 0; ii < 16; ii++){
            uint4 v = *reinterpret_cast<const uint4*>(&lCT[(size_t)tid*136 + ii*8]);
            us* pv = reinterpret_cast<us*>(&v);
            #pragma unroll
            for (int e = 0; e < 8; e++){
                if (rr == 24) pv[e] = 0;
                rr = (rr == 24) ? 0 : rr + 1;
            }
            *reinterpret_cast<uint4*>(dst + ii*8) = v;
        }
    }
}

// ======================= gemm_out3: exact round-6 proven version (256x128, triple-buffer, E/O) =======================
#define STAGE_A3(buf, kt) do { \
    _Pragma("unroll") \
    for (int c_ = 0; c_ < 4; c_++) \
        ld_g2l16(Ag + (size_t)(m0 + srow[c_])*1024 + (kt)*64 + sgr[c_]*8, \
                 &smem[(buf)*24576 + (c_*8 + wave)*512]); \
} while(0)

#define STAGE_B3(buf, kt) do { \
    _Pragma("unroll") \
    for (int c_ = 0; c_ < 2; c_++) \
        ld_g2l16(Wb + (size_t)(n0 + srow[c_])*1024 + (kt)*64 + sgr[c_]*8, \
                 &smem[(buf)*24576 + 16384 + (c_*8 + wave)*512]); \
} while(0)

#define LOAD_SET3(buf, KS, AF, BF) do { \
    _Pragma("unroll") \
    for (int i_ = 0; i_ < 4; i_++){ \
        int ra_ = wmm*64 + i_*16 + lane15; \
        int ga_ = ((KS)*4 + quad) ^ (ra_ & 7); \
        AF[i_] = *reinterpret_cast<const short8*>(&smem[(buf)*24576 + ra_*64 + ga_*8]); \
    } \
    _Pragma("unroll") \
    for (int j_ = 0; j_ < 4; j_++){ \
        int rb_ = wnn*64 + j_*16 + lane15; \
        int gb_ = ((KS)*4 + quad) ^ (rb_ & 7); \
        BF[j_] = *reinterpret_cast<const short8*>(&smem[(buf)*24576 + 16384 + rb_*64 + gb_*8]); \
    } \
} while(0)

#define MFMA_SET3(AF, BF) do { \
    __builtin_amdgcn_s_setprio(1); \
    _Pragma("unroll") \
    for (int i_ = 0; i_ < 4; i_++) \
        _Pragma("unroll") \
        for (int j_ = 0; j_ < 4; j_++) \
            acc[i_][j_] = __builtin_amdgcn_mfma_f32_16x16x32_bf16( \
                AF[i_], BF[j_], acc[i_][j_], 0, 0, 0); \
    __builtin_amdgcn_s_setprio(0); \
} while(0)

#define KLOOP3() do { \
    STAGE_A3(0, 0); STAGE_B3(0, 0); \
    STAGE_A3(1, 1); STAGE_B3(1, 1); \
    VMC6(); BAR(); \
    LOAD_SET3(0, 0, afE, bfE); LGKM0(); \
    _Pragma("unroll") \
    for (int t = 0; t < 16; t++){ \
        const int cur = t % 3, nxt = (t + 2) % 3, nx1 = (t + 1) % 3; \
        LOAD_SET3(cur, 1, afO, bfO); \
        SGB0(); \
        if (t < 14) STAGE_A3(nxt, t + 2); \
        MFMA_SET3(afE, bfE); \
        LGKM0(); \
        if (t < 14) { VMC4(); } else if (t == 14) { VMC0(); } \
        BAR(); \
        if (t < 15){ LOAD_SET3(nx1, 0, afE, bfE); SGB0(); } \
        if (t < 14) STAGE_B3(nxt, t + 2); \
        MFMA_SET3(afO, bfO); \
        LGKM0(); \
        BAR(); \
    } \
} while(0)

__global__ __launch_bounds__(512, 2) void gemm_out3(
    const us* __restrict__ Ag,
    const us* __restrict__ Wb,
    const float* __restrict__ bias,
    float* __restrict__ out)
{
    __shared__ us smem[73728];
    const int tid = threadIdx.x;
    const int lane = tid & 63;
    const int wave = tid >> 6;
    const int lane15 = lane & 15;
    const int quad = lane >> 4;
    const int wmm = wave & 3;
    const int wnn = wave >> 2;
    const int n0 = blockIdx.x * 128;
    const int m0 = blockIdx.y * 256;

    int srow[4], sgr[4];
    #pragma unroll
    for (int c = 0; c < 4; c++){
        int s = (c*8 + wave)*64 + lane;
        srow[c] = s >> 3;
        sgr[c] = (s & 7) ^ ((s >> 3) & 7);
    }

    floatx4 zero = {0.f, 0.f, 0.f, 0.f};
    floatx4 acc[4][4];
    #pragma unroll
    for (int i = 0; i < 4; i++)
        #pragma unroll
        for (int j = 0; j < 4; j++) acc[i][j] = zero;
    short8 afE[4], bfE[4], afO[4], bfO[4];

    KLOOP3();

    #pragma unroll
    for (int i = 0; i < 4; i++){
        #pragma unroll
        for (int j = 0; j < 4; j++){
            int n = n0 + wnn*64 + j*16 + lane15;
            float bvv = bias[n];
            #pragma unroll
            for (int r = 0; r < 4; r++){
                int m = m0 + wmm*64 + i*16 + quad*4 + r;
                out[(size_t)m*1024 + n] = acc[i][j][r] + bvv;
            }
        }
    }
}

// ---------------- Flash attention v3 (unchanged from round 4) ----------------
__device__ __forceinline__ short8 rdP(const us* pw, int lane15, int ks, int quad){
    const us* a = &pw[lane15*68 + ks*32 + quad*8];
    short4v lo = *reinterpret_cast<const short4v*>(a);
    short4v hi = *reinterpret_cast<const short4v*>(a + 4);
    short8 r = {lo[0], lo[1], lo[2], lo[3], hi[0], hi[1], hi[2], hi[3]};
    return r;
}

__device__ __forceinline__ void pstore_plain(floatx4 (&s)[4], us* pw, int lane15, int quad){
    #pragma unroll
    for (int tj = 0; tj < 4; tj++)
        #pragma unroll
        for (int r = 0; r < 4; r++)
            pw[(quad*4 + r)*68 + tj*16 + lane15] = f2bf(__builtin_amdgcn_exp2f(s[tj][r]));
}

__device__ __forceinline__ void pstore_diag(floatx4 (&s)[4], us* pw, int rgrow, int j0,
                                            int lane15, int quad){
    #pragma unroll
    for (int tj = 0; tj < 4; tj++){
        #pragma unroll
        for (int r = 0; r < 4; r++){
            float p = __builtin_amdgcn_exp2f(s[tj][r]);
            bool kill = (j0 + tj*16 + lane15) > (rgrow + quad*4 + r);
            pw[(quad*4 + r)*68 + tj*16 + lane15] = f2bf(kill ? 0.f : p);
        }
    }
}

#define ATT_STAGE(itn) do { \
    _Pragma("unroll") \
    for (int i_ = 0; i_ < 2; i_++){ \
        ld_g2l16(kb + (size_t)((itn)*64 + srow[i_])*64 + sgr[i_]*8, &lK[(itn) & 1][(i_*4 + wave)*512]); \
        ld_g2l16(vb + (size_t)srow[i_]*2048 + (itn)*64 + sgr[i_]*8, &lV[(itn) & 1][(i_*4 + wave)*512]); \
    } } while(0)

// MODE 0: both rg, no diag. MODE 1: rg0 diag, rg1 plain. MODE 2: rg1 diag, rg0 inactive.
#define ATT_BODY(MODE, ITV) do { \
    const int j0_ = (ITV)*64; \
    __syncthreads(); \
    if ((ITV) + 1 < nIter) ATT_STAGE((ITV) + 1); \
    const us* Kb = lK[(ITV) & 1]; \
    const us* Vb = lV[(ITV) & 1]; \
    floatx4 s0[4], s1[4]; \
    __builtin_amdgcn_s_setprio(1); \
    _Pragma("unroll") \
    for (int tj = 0; tj < 4; tj++){ \
        int rk = tj*16 + lane15; \
        short8 kf0 = *reinterpret_cast<const short8*>(&Kb[rk*64 + ((quad     ^ (rk & 7)))*8]); \
        short8 kf1 = *reinterpret_cast<const short8*>(&Kb[rk*64 + (((4+quad) ^ (rk & 7)))*8]); \
        floatx4 z1 = __builtin_amdgcn_mfma_f32_16x16x32_bf16(qf1a, kf0, zero, 0, 0, 0); \
        s1[tj]     = __builtin_amdgcn_mfma_f32_16x16x32_bf16(qf1b, kf1, z1,   0, 0, 0); \
        if ((MODE) != 2){ \
            floatx4 z0 = __builtin_amdgcn_mfma_f32_16x16x32_bf16(qf0a, kf0, zero, 0, 0, 0); \
            s0[tj]     = __builtin_amdgcn_mfma_f32_16x16x32_bf16(qf0b, kf1, z0,   0, 0, 0); \
        } \
    } \
    __builtin_amdgcn_s_setprio(0); \
    if ((MODE) == 2)      pstore_diag(s1, pw1, rg1, j0_, lane15, quad); \
    else                  pstore_plain(s1, pw1, lane15, quad); \
    if ((MODE) == 1)      pstore_diag(s0, pw0, rg0, j0_, lane15, quad); \
    else if ((MODE) == 0) pstore_plain(s0, pw0, lane15, quad); \
    __builtin_amdgcn_s_setprio(1); \
    _Pragma("unroll") \
    for (int ks = 0; ks < 2; ks++){ \
        short8 mfr = *reinterpret_cast<const short8*>(&lmask[j0_ + ks*32 + quad*8]); \
        short8 pf1 = rdP(pw1, lane15, ks, quad); \
        short8 pf0; \
        lacc1 = __builtin_amdgcn_mfma_f32_16x16x32_bf16(pf1, mfr, lacc1, 0, 0, 0); \
        if ((MODE) != 2){ \
            pf0 = rdP(pw0, lane15, ks, quad); \
            lacc0 = __builtin_amdgcn_mfma_f32_16x16x32_bf16(pf0, mfr, lacc0, 0, 0, 0); \
        } \
        _Pragma("unroll") \
        for (int dt = 0; dt < 4; dt++){ \
            int rv = dt*16 + lane15; \
            short8 vf = *reinterpret_cast<const short8*>(&Vb[rv*64 + (((ks*4+quad) ^ (rv & 7)))*8]); \
            acc1[dt] = __builtin_amdgcn_mfma_f32_16x16x32_bf16(pf1, vf, acc1[dt], 0, 0, 0); \
            if ((MODE) != 2) acc0[dt] = __builtin_amdgcn_mfma_f32_16x16x32_bf16(pf0, vf, acc0[dt], 0, 0, 0); \
        } \
    } \
    __builtin_amdgcn_s_setprio(0); \
} while(0)

__global__ __launch_bounds__(256, 3) void flash_attn(
    const us* __restrict__ q,
    const us* __restrict__ k,
    const us* __restrict__ vT,
    us* __restrict__ y)
{
    __shared__ us lK[2][64*64];        // double-buffered K tile (XOR-swizzled)
    __shared__ us lV[2][64*64];        // double-buffered V^T tile
    __shared__ us lP[4][2][16*68];     // per-wave P buffers (stride 68)
    __shared__ us lmask[2048];         // bf16 column mask: t%25==24 -> 0 else 1
    const int tid = threadIdx.x;
    const int lane = tid & 63;
    const int wave = tid >> 6;
    const int lane15 = lane & 15;
    const int quad = lane >> 4;
    const int lin = blockIdx.x;        // grid 1024 = 16 qtiles x 64 bh, longest-first
    const int qt2 = 15 - (lin >> 6);
    const int bh = lin & 63;
    const int b = bh >> 4, h = bh & 15;
    const int rg0 = qt2*128 + wave*16;
    const int rg1 = rg0 + 64;
    const int nIter = 2*qt2 + 2;

    const us* kb = k  + (size_t)bh*2048*64;
    const us* vb = vT + (size_t)bh*64*2048;

    // build column-mask table (ordered before first use by the loop-head __syncthreads)
    {
        int c0 = tid * 8;
        int rr = c0 % 25;
        ushort4 mv[2];
        us* pm = reinterpret_cast<us*>(mv);
        #pragma unroll
        for (int e = 0; e < 8; e++){
            pm[e] = (rr == 24) ? (us)0 : (us)0x3F80;
            rr = (rr == 24) ? 0 : rr + 1;
        }
        *reinterpret_cast<uint4*>(&lmask[c0]) = *reinterpret_cast<uint4*>(mv);
    }

    floatx4 zero = {0.f, 0.f, 0.f, 0.f};
    us* pw0 = &lP[wave][0][0];
    us* pw1 = &lP[wave][1][0];

    int srow[2], sgr[2];
    #pragma unroll
    for (int i = 0; i < 2; i++){
        int s = (i*4 + wave)*64 + lane;
        srow[i] = s >> 3;
        sgr[i] = (s & 7) ^ ((s >> 3) & 7);
    }

    const us* q0 = q + ((size_t)b*2048 + rg0 + lane15)*1024 + h*64 + quad*8;
    const us* q1 = q + ((size_t)b*2048 + rg1 + lane15)*1024 + h*64 + quad*8;
    short8 qf0a = *reinterpret_cast<const short8*>(q0);
    short8 qf0b = *reinterpret_cast<const short8*>(q0 + 32);
    short8 qf1a = *reinterpret_cast<const short8*>(q1);
    short8 qf1b = *reinterpret_cast<const short8*>(q1 + 32);

    floatx4 acc0[4], acc1[4];
    #pragma unroll
    for (int d = 0; d < 4; d++){ acc0[d] = zero; acc1[d] = zero; }
    floatx4 lacc0 = zero, lacc1 = zero;

    // pre-stage tile 0 into buffer 0
    ATT_STAGE(0);

    int it = 0;
    #pragma unroll 1
    for (; it < nIter - 2; it++) ATT_BODY(0, it);
    ATT_BODY(1, it); it++;
    ATT_BODY(2, it);

    float rl0[4], rl1[4];
    #pragma unroll
    for (int r = 0; r < 4; r++){ rl0[r] = 1.0f / lacc0[r]; rl1[r] = 1.0f / lacc1[r]; }
    #pragma unroll
    for (int dt = 0; dt < 4; dt++){
        #pragma unroll
        for (int r = 0; r < 4; r++){
            int t0 = rg0 + quad*4 + r;
            int t1 = rg1 + quad*4 + r;
            int cc = h*64 + dt*16 + lane15;
            y[((size_t)b*2048 + t0)*1024 + cc] = f2bf(acc0[dt][r] * rl0[r]);
            y[((size_t)b*2048 + t1)*1024 + cc] = f2bf(acc1[dt][r] * rl1[r]);
        }
    }
}

// ---------------- launch ----------------
extern "C" void kernel_launch(void* const* d_in, const int* in_sizes, int n_in,
                              void* d_out, int out_size, void* d_ws, size_t ws_size,
                              hipStream_t stream)
{
    const float* x  = (const float*)d_in[0];
    const float* Wq = (const float*)d_in[1];
    const float* bq = (const float*)d_in[2];
    const float* Wk = (const float*)d_in[3];
    const float* bk = (const float*)d_in[4];
    const float* Wv = (const float*)d_in[5];
    const float* bv = (const float*)d_in[6];
    const float* Wp = (const float*)d_in[7];
    const float* bp = (const float*)d_in[8];
    float* out = (float*)d_out;

    us* ws  = (us*)d_ws;
    us* xbf = ws;                          // [8192,1024]
    us* wqb = xbf + (size_t)8192*1024;
    us* wkb = wqb + (size_t)1024*1024;
    us* wvb = wkb + (size_t)1024*1024;
    us* wpb = wvb + (size_t)1024*1024;
    us* qws = wpb + (size_t)1024*1024;     // q [B,T,C] bf16 (pre-scaled, exp2 domain)
    us* kws = qws + (size_t)8388608;       // k [B,H,T,64]
    us* vtw = kws + (size_t)8388608;       // vT [B,H,64,T] (RL-masked cols zeroed)
    us* yws = vtw + (size_t)8388608;       // y [B,T,C] bf16

    cvt_kernel<<<8192, 256, 0, stream>>>(x, xbf, 2097152);
    cvt4_kernel<<<4096, 256, 0, stream>>>(Wq, Wk, Wv, Wp, wqb, wkb, wvb, wpb);

    gemm_qkv5<<<dim3(12, 64), 256, 0, stream>>>(xbf, wqb, wkb, wvb, bq, bk, bv, qws, kws, vtw);

    flash_attn<<<1024, 256, 0, stream>>>(qws, kws, vtw, yws);

    gemm_out3<<<dim3(8, 32), 512, 0, stream>>>(yws, wpb, bp, out);
}

// Round 11
// 253.098 us; speedup vs baseline: 2.6081x; 1.0041x over previous
//
#include <hip/hip_runtime.h>
#include <hip/hip_bf16.h>

// B=4, T=2048, C=1024, H=16, HD=64. JOINED_DIM=25 (mask col%25==24 -> masked).

typedef __attribute__((ext_vector_type(8))) short short8;
typedef __attribute__((ext_vector_type(4))) short short4v;
typedef __attribute__((ext_vector_type(4))) float floatx4;
typedef unsigned short us;

__device__ __forceinline__ us f2bf(float f){
    union { __hip_bfloat16 h; us u; } cv;
    cv.h = __float2bfloat16(f);
    return cv.u;
}

__device__ __forceinline__ void ld_g2l16(const void* g, void* l){
    __builtin_amdgcn_global_load_lds((const __attribute__((address_space(1))) void*)g,
                                     (__attribute__((address_space(3))) void*)l, 16, 0, 0);
}

// ---------------- fp32 -> bf16 conversion (single merged kernel: x + 4 weight matrices) ----------------
__global__ __launch_bounds__(256) void cvt_all(
    const float* __restrict__ x,
    const float* __restrict__ w0, const float* __restrict__ w1,
    const float* __restrict__ w2, const float* __restrict__ w3,
    us* __restrict__ xo,
    us* __restrict__ o0, us* __restrict__ o1,
    us* __restrict__ o2, us* __restrict__ o3)
{
    int bid = blockIdx.x;
    const float* src;
    us* dst;
    int i;
    if (bid < 8192){
        src = x; dst = xo;
        i = bid * 256 + threadIdx.x;
    } else {
        int wb = bid - 8192;
        int wsel = wb >> 10;
        i = (wb & 1023) * 256 + threadIdx.x;
        src = (wsel == 0) ? w0 : (wsel == 1) ? w1 : (wsel == 2) ? w2 : w3;
        dst = (wsel == 0) ? o0 : (wsel == 1) ? o1 : (wsel == 2) ? o2 : o3;
    }
    float4 v = reinterpret_cast<const float4*>(src)[i];
    ushort4 o;
    o.x = f2bf(v.x); o.y = f2bf(v.y); o.z = f2bf(v.z); o.w = f2bf(v.w);
    reinterpret_cast<ushort4*>(dst)[i] = o;
}

#define QSCALE 0.1803368801111244f

#define BAR() __builtin_amdgcn_s_barrier()
#define SGB0() __builtin_amdgcn_sched_barrier(0)
#define LGKM0() do { asm volatile("s_waitcnt lgkmcnt(0)" ::: "memory"); __builtin_amdgcn_sched_barrier(0); } while(0)
#define VMC6() asm volatile("s_waitcnt vmcnt(6)" ::: "memory")
#define VMC4() asm volatile("s_waitcnt vmcnt(4)" ::: "memory")
#define VMC0() asm volatile("s_waitcnt vmcnt(0)" ::: "memory")

// ======================= round-6 proven template: 256x128 tile, tri-buffer + E/O read-ahead =======================
// Best measured qkv component (R6: 65.0 us, VGPR 92, MfmaUtil 32.5%). 8 waves (4M x 2N,
// wave 64x64), LDS 3 x 24 KiB = 144 KiB, 2 phases/K-tile:
//   P1(t): readO(cur,ks1) | stage A(t+2) | MFMA(E) | lgkm0 | vmcnt(4) | bar
//   P2(t): readE(t+1,ks0) | stage B(t+2) | MFMA(O) | lgkm0 | bar
// vmcnt(4)@P1 drains tile t+1 (leaves A(t+2) in flight); WAR: buf (t+2)%3's last reads are
// P1(t-1)'s O-set, lgkm-drained before that barrier.

#define STAGE_A3(buf, kt) do { \
    _Pragma("unroll") \
    for (int c_ = 0; c_ < 4; c_++) \
        ld_g2l16(Ag + (size_t)(m0 + srow[c_])*1024 + (kt)*64 + sgr[c_]*8, \
                 &smem[(buf)*24576 + (c_*8 + wave)*512]); \
} while(0)

#define STAGE_B3(buf, kt) do { \
    _Pragma("unroll") \
    for (int c_ = 0; c_ < 2; c_++) \
        ld_g2l16(Wb + (size_t)(n0 + srow[c_])*1024 + (kt)*64 + sgr[c_]*8, \
                 &smem[(buf)*24576 + 16384 + (c_*8 + wave)*512]); \
} while(0)

#define LOAD_SET3(buf, KS, AF, BF) do { \
    _Pragma("unroll") \
    for (int i_ = 0; i_ < 4; i_++){ \
        int ra_ = wmm*64 + i_*16 + lane15; \
        int ga_ = ((KS)*4 + quad) ^ (ra_ & 7); \
        AF[i_] = *reinterpret_cast<const short8*>(&smem[(buf)*24576 + ra_*64 + ga_*8]); \
    } \
    _Pragma("unroll") \
    for (int j_ = 0; j_ < 4; j_++){ \
        int rb_ = wnn*64 + j_*16 + lane15; \
        int gb_ = ((KS)*4 + quad) ^ (rb_ & 7); \
        BF[j_] = *reinterpret_cast<const short8*>(&smem[(buf)*24576 + 16384 + rb_*64 + gb_*8]); \
    } \
} while(0)

#define MFMA_SET3(AF, BF) do { \
    __builtin_amdgcn_s_setprio(1); \
    _Pragma("unroll") \
    for (int i_ = 0; i_ < 4; i_++) \
        _Pragma("unroll") \
        for (int j_ = 0; j_ < 4; j_++) \
            acc[i_][j_] = __builtin_amdgcn_mfma_f32_16x16x32_bf16( \
                AF[i_], BF[j_], acc[i_][j_], 0, 0, 0); \
    __builtin_amdgcn_s_setprio(0); \
} while(0)

#define KLOOP3() do { \
    STAGE_A3(0, 0); STAGE_B3(0, 0); \
    STAGE_A3(1, 1); STAGE_B3(1, 1); \
    VMC6(); BAR(); \
    LOAD_SET3(0, 0, afE, bfE); LGKM0(); \
    _Pragma("unroll") \
    for (int t = 0; t < 16; t++){ \
        const int cur = t % 3, nxt = (t + 2) % 3, nx1 = (t + 1) % 3; \
        LOAD_SET3(cur, 1, afO, bfO); \
        SGB0(); \
        if (t < 14) STAGE_A3(nxt, t + 2); \
        MFMA_SET3(afE, bfE); \
        LGKM0(); \
        if (t < 14) { VMC4(); } else if (t == 14) { VMC0(); } \
        BAR(); \
        if (t < 15){ LOAD_SET3(nx1, 0, afE, bfE); SGB0(); } \
        if (t < 14) STAGE_B3(nxt, t + 2); \
        MFMA_SET3(afO, bfO); \
        LGKM0(); \
        BAR(); \
    } \
} while(0)

__global__ __launch_bounds__(512, 2) void gemm_qkv3(
    const us* __restrict__ Ag,
    const us* __restrict__ Wqb, const us* __restrict__ Wkb, const us* __restrict__ Wvb,
    const float* __restrict__ bq, const float* __restrict__ bk, const float* __restrict__ bv,
    us* __restrict__ qo, us* __restrict__ ko, us* __restrict__ vto)
{
    __shared__ us smem[73728];   // 3 x (A 16384 us + B 8192 us) = 144 KiB
    const int tid = threadIdx.x;
    const int lane = tid & 63;
    const int wave = tid >> 6;        // 0..7
    const int lane15 = lane & 15;
    const int quad = lane >> 4;
    const int wmm = wave & 3;         // 0..3 (64 rows each)
    const int wnn = wave >> 2;        // 0..1 (64 cols each)
    const int seg = blockIdx.x >> 3;          // 0=Q 1=K 2=V
    const int n0 = (blockIdx.x & 7) * 128;
    const int m0 = blockIdx.y * 256;

    const us* Wb = (seg == 0) ? Wqb : (seg == 1) ? Wkb : Wvb;
    const float* bias = (seg == 0) ? bq : (seg == 1) ? bk : bv;

    int srow[4], sgr[4];
    #pragma unroll
    for (int c = 0; c < 4; c++){
        int s = (c*8 + wave)*64 + lane;
        srow[c] = s >> 3;
        sgr[c] = (s & 7) ^ ((s >> 3) & 7);
    }

    floatx4 zero = {0.f, 0.f, 0.f, 0.f};
    floatx4 acc[4][4];
    #pragma unroll
    for (int i = 0; i < 4; i++)
        #pragma unroll
        for (int j = 0; j < 4; j++) acc[i][j] = zero;
    short8 afE[4], bfE[4], afO[4], bfO[4];

    KLOOP3();

    if (seg < 2){
        #pragma unroll
        for (int i = 0; i < 4; i++){
            #pragma unroll
            for (int j = 0; j < 4; j++){
                int n = n0 + wnn*64 + j*16 + lane15;
                float bvv = bias[n];
                #pragma unroll
                for (int r = 0; r < 4; r++){
                    int m = m0 + wmm*64 + i*16 + quad*4 + r;
                    float val = acc[i][j][r] + bvv;
                    if (seg == 0){
                        qo[(size_t)m*1024 + n] = f2bf(val * QSCALE);
                    } else {
                        int b = m >> 11, tt = m & 2047;
                        int h = n >> 6,  d = n & 63;
                        ko[(((size_t)b*16 + h)*2048 + tt)*64 + d] = f2bf(val);
                    }
                }
            }
        }
    } else {
        // V^T epilogue: transpose via LDS; ALSO zero RL-masked columns (t%25==24).
        us* lCT = smem;                  // [128 n][264 us] = 67.6 KB
        const int b = m0 >> 11;
        const int t0 = m0 & 2047;
        #pragma unroll
        for (int j = 0; j < 4; j++){
            int nl = wnn*64 + j*16 + lane15;
            float bvv = bias[n0 + nl];
            #pragma unroll
            for (int i = 0; i < 4; i++){
                int ml = wmm*64 + i*16 + quad*4;
                unsigned int lo = (unsigned int)f2bf(acc[i][j][0] + bvv) |
                                  ((unsigned int)f2bf(acc[i][j][1] + bvv) << 16);
                unsigned int hi = (unsigned int)f2bf(acc[i][j][2] + bvv) |
                                  ((unsigned int)f2bf(acc[i][j][3] + bvv) << 16);
                uint2 pk2; pk2.x = lo; pk2.y = hi;
                *reinterpret_cast<uint2*>(&lCT[(size_t)nl*264 + ml]) = pk2;
            }
        }
        __syncthreads();
        int nl = tid >> 2;           // 0..127
        int c4 = tid & 3;            // 64-us segment of the 256-wide row
        int nC = n0 + nl;
        int h = nC >> 6, d = nC & 63;
        us* dst = vto + (((size_t)b*16 + h)*64 + d)*2048 + t0 + c4*64;
        int rr = (t0 + c4*64) % 25;
        #pragma unroll
        for (int ii = 0; ii < 8; ii++){
            uint4 v = *reinterpret_cast<const uint4*>(&lCT[(size_t)nl*264 + c4*64 + ii*8]);
            us* pv = reinterpret_cast<us*>(&v);
            #pragma unroll
            for (int e = 0; e < 8; e++){
                if (rr == 24) pv[e] = 0;
                rr = (rr == 24) ? 0 : rr + 1;
            }
            *reinterpret_cast<uint4*>(dst + ii*8) = v;
        }
    }
}

// ======================= gemm_out3: round-6 proven version (256x128, triple-buffer, E/O) =======================
__global__ __launch_bounds__(512, 2) void gemm_out3(
    const us* __restrict__ Ag,
    const us* __restrict__ Wb,
    const float* __restrict__ bias,
    float* __restrict__ out)
{
    __shared__ us smem[73728];
    const int tid = threadIdx.x;
    const int lane = tid & 63;
    const int wave = tid >> 6;
    const int lane15 = lane & 15;
    const int quad = lane >> 4;
    const int wmm = wave & 3;
    const int wnn = wave >> 2;
    const int n0 = blockIdx.x * 128;
    const int m0 = blockIdx.y * 256;

    int srow[4], sgr[4];
    #pragma unroll
    for (int c = 0; c < 4; c++){
        int s = (c*8 + wave)*64 + lane;
        srow[c] = s >> 3;
        sgr[c] = (s & 7) ^ ((s >> 3) & 7);
    }

    floatx4 zero = {0.f, 0.f, 0.f, 0.f};
    floatx4 acc[4][4];
    #pragma unroll
    for (int i = 0; i < 4; i++)
        #pragma unroll
        for (int j = 0; j < 4; j++) acc[i][j] = zero;
    short8 afE[4], bfE[4], afO[4], bfO[4];

    KLOOP3();

    #pragma unroll
    for (int i = 0; i < 4; i++){
        #pragma unroll
        for (int j = 0; j < 4; j++){
            int n = n0 + wnn*64 + j*16 + lane15;
            float bvv = bias[n];
            #pragma unroll
            for (int r = 0; r < 4; r++){
                int m = m0 + wmm*64 + i*16 + quad*4 + r;
                out[(size_t)m*1024 + n] = acc[i][j][r] + bvv;
            }
        }
    }
}

// ---------------- Flash attention v3 (round-4 version, unchanged) ----------------
__device__ __forceinline__ short8 rdP(const us* pw, int lane15, int ks, int quad){
    const us* a = &pw[lane15*68 + ks*32 + quad*8];
    short4v lo = *reinterpret_cast<const short4v*>(a);
    short4v hi = *reinterpret_cast<const short4v*>(a + 4);
    short8 r = {lo[0], lo[1], lo[2], lo[3], hi[0], hi[1], hi[2], hi[3]};
    return r;
}

__device__ __forceinline__ void pstore_plain(floatx4 (&s)[4], us* pw, int lane15, int quad){
    #pragma unroll
    for (int tj = 0; tj < 4; tj++)
        #pragma unroll
        for (int r = 0; r < 4; r++)
            pw[(quad*4 + r)*68 + tj*16 + lane15] = f2bf(__builtin_amdgcn_exp2f(s[tj][r]));
}

__device__ __forceinline__ void pstore_diag(floatx4 (&s)[4], us* pw, int rgrow, int j0,
                                            int lane15, int quad){
    #pragma unroll
    for (int tj = 0; tj < 4; tj++){
        #pragma unroll
        for (int r = 0; r < 4; r++){
            float p = __builtin_amdgcn_exp2f(s[tj][r]);
            bool kill = (j0 + tj*16 + lane15) > (rgrow + quad*4 + r);
            pw[(quad*4 + r)*68 + tj*16 + lane15] = f2bf(kill ? 0.f : p);
        }
    }
}

#define ATT_STAGE(itn) do { \
    _Pragma("unroll") \
    for (int i_ = 0; i_ < 2; i_++){ \
        ld_g2l16(kb + (size_t)((itn)*64 + srow[i_])*64 + sgr[i_]*8, &lK[(itn) & 1][(i_*4 + wave)*512]); \
        ld_g2l16(vb + (size_t)srow[i_]*2048 + (itn)*64 + sgr[i_]*8, &lV[(itn) & 1][(i_*4 + wave)*512]); \
    } } while(0)

// MODE 0: both rg, no diag. MODE 1: rg0 diag, rg1 plain. MODE 2: rg1 diag, rg0 inactive.
#define ATT_BODY(MODE, ITV) do { \
    const int j0_ = (ITV)*64; \
    __syncthreads(); \
    if ((ITV) + 1 < nIter) ATT_STAGE((ITV) + 1); \
    const us* Kb = lK[(ITV) & 1]; \
    const us* Vb = lV[(ITV) & 1]; \
    floatx4 s0[4], s1[4]; \
    __builtin_amdgcn_s_setprio(1); \
    _Pragma("unroll") \
    for (int tj = 0; tj < 4; tj++){ \
        int rk = tj*16 + lane15; \
        short8 kf0 = *reinterpret_cast<const short8*>(&Kb[rk*64 + ((quad     ^ (rk & 7)))*8]); \
        short8 kf1 = *reinterpret_cast<const short8*>(&Kb[rk*64 + (((4+quad) ^ (rk & 7)))*8]); \
        floatx4 z1 = __builtin_amdgcn_mfma_f32_16x16x32_bf16(qf1a, kf0, zero, 0, 0, 0); \
        s1[tj]     = __builtin_amdgcn_mfma_f32_16x16x32_bf16(qf1b, kf1, z1,   0, 0, 0); \
        if ((MODE) != 2){ \
            floatx4 z0 = __builtin_amdgcn_mfma_f32_16x16x32_bf16(qf0a, kf0, zero, 0, 0, 0); \
            s0[tj]     = __builtin_amdgcn_mfma_f32_16x16x32_bf16(qf0b, kf1, z0,   0, 0, 0); \
        } \
    } \
    __builtin_amdgcn_s_setprio(0); \
    if ((MODE) == 2)      pstore_diag(s1, pw1, rg1, j0_, lane15, quad); \
    else                  pstore_plain(s1, pw1, lane15, quad); \
    if ((MODE) == 1)      pstore_diag(s0, pw0, rg0, j0_, lane15, quad); \
    else if ((MODE) == 0) pstore_plain(s0, pw0, lane15, quad); \
    __builtin_amdgcn_s_setprio(1); \
    _Pragma("unroll") \
    for (int ks = 0; ks < 2; ks++){ \
        short8 mfr = *reinterpret_cast<const short8*>(&lmask[j0_ + ks*32 + quad*8]); \
        short8 pf1 = rdP(pw1, lane15, ks, quad); \
        short8 pf0; \
        lacc1 = __builtin_amdgcn_mfma_f32_16x16x32_bf16(pf1, mfr, lacc1, 0, 0, 0); \
        if ((MODE) != 2){ \
            pf0 = rdP(pw0, lane15, ks, quad); \
            lacc0 = __builtin_amdgcn_mfma_f32_16x16x32_bf16(pf0, mfr, lacc0, 0, 0, 0); \
        } \
        _Pragma("unroll") \
        for (int dt = 0; dt < 4; dt++){ \
            int rv = dt*16 + lane15; \
            short8 vf = *reinterpret_cast<const short8*>(&Vb[rv*64 + (((ks*4+quad) ^ (rv & 7)))*8]); \
            acc1[dt] = __builtin_amdgcn_mfma_f32_16x16x32_bf16(pf1, vf, acc1[dt], 0, 0, 0); \
            if ((MODE) != 2) acc0[dt] = __builtin_amdgcn_mfma_f32_16x16x32_bf16(pf0, vf, acc0[dt], 0, 0, 0); \
        } \
    } \
    __builtin_amdgcn_s_setprio(0); \
} while(0)

__global__ __launch_bounds__(256, 3) void flash_attn(
    const us* __restrict__ q,
    const us* __restrict__ k,
    const us* __restrict__ vT,
    us* __restrict__ y)
{
    __shared__ us lK[2][64*64];        // double-buffered K tile (XOR-swizzled)
    __shared__ us lV[2][64*64];        // double-buffered V^T tile
    __shared__ us lP[4][2][16*68];     // per-wave P buffers (stride 68)
    __shared__ us lmask[2048];         // bf16 column mask: t%25==24 -> 0 else 1
    const int tid = threadIdx.x;
    const int lane = tid & 63;
    const int wave = tid >> 6;
    const int lane15 = lane & 15;
    const int quad = lane >> 4;
    const int lin = blockIdx.x;        // grid 1024 = 16 qtiles x 64 bh, longest-first
    const int qt2 = 15 - (lin >> 6);
    const int bh = lin & 63;
    const int b = bh >> 4, h = bh & 15;
    const int rg0 = qt2*128 + wave*16;
    const int rg1 = rg0 + 64;
    const int nIter = 2*qt2 + 2;

    const us* kb = k  + (size_t)bh*2048*64;
    const us* vb = vT + (size_t)bh*64*2048;

    // build column-mask table (ordered before first use by the loop-head __syncthreads)
    {
        int c0 = tid * 8;
        int rr = c0 % 25;
        ushort4 mv[2];
        us* pm = reinterpret_cast<us*>(mv);
        #pragma unroll
        for (int e = 0; e < 8; e++){
            pm[e] = (rr == 24) ? (us)0 : (us)0x3F80;
            rr = (rr == 24) ? 0 : rr + 1;
        }
        *reinterpret_cast<uint4*>(&lmask[c0]) = *reinterpret_cast<uint4*>(mv);
    }

    floatx4 zero = {0.f, 0.f, 0.f, 0.f};
    us* pw0 = &lP[wave][0][0];
    us* pw1 = &lP[wave][1][0];

    int srow[2], sgr[2];
    #pragma unroll
    for (int i = 0; i < 2; i++){
        int s = (i*4 + wave)*64 + lane;
        srow[i] = s >> 3;
        sgr[i] = (s & 7) ^ ((s >> 3) & 7);
    }

    const us* q0 = q + ((size_t)b*2048 + rg0 + lane15)*1024 + h*64 + quad*8;
    const us* q1 = q + ((size_t)b*2048 + rg1 + lane15)*1024 + h*64 + quad*8;
    short8 qf0a = *reinterpret_cast<const short8*>(q0);
    short8 qf0b = *reinterpret_cast<const short8*>(q0 + 32);
    short8 qf1a = *reinterpret_cast<const short8*>(q1);
    short8 qf1b = *reinterpret_cast<const short8*>(q1 + 32);

    floatx4 acc0[4], acc1[4];
    #pragma unroll
    for (int d = 0; d < 4; d++){ acc0[d] = zero; acc1[d] = zero; }
    floatx4 lacc0 = zero, lacc1 = zero;

    // pre-stage tile 0 into buffer 0
    ATT_STAGE(0);

    int it = 0;
    #pragma unroll 1
    for (; it < nIter - 2; it++) ATT_BODY(0, it);
    ATT_BODY(1, it); it++;
    ATT_BODY(2, it);

    float rl0[4], rl1[4];
    #pragma unroll
    for (int r = 0; r < 4; r++){ rl0[r] = 1.0f / lacc0[r]; rl1[r] = 1.0f / lacc1[r]; }
    #pragma unroll
    for (int dt = 0; dt < 4; dt++){
        #pragma unroll
        for (int r = 0; r < 4; r++){
            int t0 = rg0 + quad*4 + r;
            int t1 = rg1 + quad*4 + r;
            int cc = h*64 + dt*16 + lane15;
            y[((size_t)b*2048 + t0)*1024 + cc] = f2bf(acc0[dt][r] * rl0[r]);
            y[((size_t)b*2048 + t1)*1024 + cc] = f2bf(acc1[dt][r] * rl1[r]);
        }
    }
}

// ---------------- launch ----------------
extern "C" void kernel_launch(void* const* d_in, const int* in_sizes, int n_in,
                              void* d_out, int out_size, void* d_ws, size_t ws_size,
                              hipStream_t stream)
{
    const float* x  = (const float*)d_in[0];
    const float* Wq = (const float*)d_in[1];
    const float* bq = (const float*)d_in[2];
    const float* Wk = (const float*)d_in[3];
    const float* bk = (const float*)d_in[4];
    const float* Wv = (const float*)d_in[5];
    const float* bv = (const float*)d_in[6];
    const float* Wp = (const float*)d_in[7];
    const float* bp = (const float*)d_in[8];
    float* out = (float*)d_out;

    us* ws  = (us*)d_ws;
    us* xbf = ws;                          // [8192,1024]
    us* wqb = xbf + (size_t)8192*1024;
    us* wkb = wqb + (size_t)1024*1024;
    us* wvb = wkb + (size_t)1024*1024;
    us* wpb = wvb + (size_t)1024*1024;
    us* qws = wpb + (size_t)1024*1024;     // q [B,T,C] bf16 (pre-scaled, exp2 domain)
    us* kws = qws + (size_t)8388608;       // k [B,H,T,64]
    us* vtw = kws + (size_t)8388608;       // vT [B,H,64,T] (RL-masked cols zeroed)
    us* yws = vtw + (size_t)8388608;       // y [B,T,C] bf16

    cvt_all<<<12288, 256, 0, stream>>>(x, Wq, Wk, Wv, Wp, xbf, wqb, wkb, wvb, wpb);

    gemm_qkv3<<<dim3(24, 32), 512, 0, stream>>>(xbf, wqb, wkb, wvb, bq, bk, bv, qws, kws, vtw);

    flash_attn<<<1024, 256, 0, stream>>>(qws, kws, vtw, yws);

    gemm_out3<<<dim3(8, 32), 512, 0, stream>>>(yws, wpb, bp, out);
}